// Round 5
// baseline (2365.472 us; speedup 1.0000x reference)
//
#include <hip/hip_runtime.h>
#include <hip/hip_bf16.h>

// Q_NsNet2: fake-quantized FC + 2xGRU + FC stack.
// OUTPUT IS FLOAT32 (reference returns f32; rounds 0-4 failed by writing bf16
// into a float buffer -> upper half stayed zero -> constant 0.90625 error).
//
// Representation: every quantized tensor is stored RAW (fp32) + per-tensor
// absmax; consumers apply fq on load. Matches reference up to fp32
// accumulation-order noise.
//
// Workspace (floats): AM[128] | X[400*4096] | pool[3*400*4096] = 26.2 MB
//   slots 0..34 input amax, 35..91 intermediate amax, 120 magic.

#define BATCH_N 4096
#define R4 (400 * 4096)
#define R6 (600 * 4096)
#define MAGIC 123.0f

__device__ __forceinline__ float qscale(const float* am) { return am[0] / 127.0f + 1e-12f; }

__device__ __forceinline__ float fq1(float x, float s) {
    float q = rintf(x / s);                    // round-half-even, IEEE divide
    q = fminf(fmaxf(q, -127.0f), 127.0f);
    return q * s;
}

__device__ __forceinline__ float sigm(float x) {
    if (x >= 0.f) { float e = expf(-x); return 1.0f / (1.0f + e); }
    float e = expf(x); return e / (1.0f + e);
}

__device__ __forceinline__ float wave_max64(float v) {
#pragma unroll
    for (int off = 32; off > 0; off >>= 1)
        v = fmaxf(v, __shfl_down(v, off, 64));
    return v;
}

// Block-wide absmax -> one atomicMax per block (float-as-uint: exact for >=0).
__device__ __forceinline__ void block_amax(float v, float* slot, float* sd) {
    v = wave_max64(v);
    int lane = threadIdx.x & 63, w = threadIdx.x >> 6;
    if (lane == 0) sd[w] = v;
    __syncthreads();
    if (threadIdx.x == 0) {
        int nw = blockDim.x >> 6;
        float m = sd[0];
        for (int i = 1; i < nw; ++i) m = fmaxf(m, sd[i]);
        atomicMax((unsigned int*)slot, __float_as_uint(m));
    }
}

__global__ void k_init(float* am) {
    int t = threadIdx.x;
    if (t < 128) am[t] = (t == 120) ? MAGIC : 0.f;
}

__global__ void k_fill(float* out, int n, float c) {   // ws-too-small diagnostic
    int i = blockIdx.x * 256 + threadIdx.x;
    if (i < n) out[i] = c;
}

// ---- input absmax: ONE block per tensor, plain store (no atomics, no init dep) ----
struct AbsmaxArgs {
    const float* p[35];
    int n[35];
    float* am;
};

__global__ __launch_bounds__(256) void absmax_multi(AbsmaxArgs a) {
    int t = blockIdx.x;
    const float* p = a.p[t];
    int n = a.n[t];
    int nv = n >> 2;
    float v = 0.f;
    for (int i = threadIdx.x; i < nv; i += 256) {
        float4 x = *(const float4*)(p + i * 4);
        v = fmaxf(v, fmaxf(fmaxf(fabsf(x.x), fabsf(x.y)), fmaxf(fabsf(x.z), fabsf(x.w))));
    }
    for (int i = nv * 4 + threadIdx.x; i < n; i += 256)
        v = fmaxf(v, fabsf(p[i]));
    v = wave_max64(v);
    __shared__ float sd[4];
    int lane = threadIdx.x & 63, w = threadIdx.x >> 6;
    if (lane == 0) sd[w] = v;
    __syncthreads();
    if (threadIdx.x == 0)
        a.am[t] = fmaxf(fmaxf(sd[0], sd[1]), fmaxf(sd[2], sd[3]));   // plain store
}

// ---------------- GEMM: out = fq(W) @ fq(X), fused absmax(out) ----------------
#define BM 64
#define BN 64
#define BK 16

__global__ __launch_bounds__(256) void gemm_fq(
    const float* __restrict__ W, const float* __restrict__ amW,
    const float* __restrict__ X, const float* __restrict__ amX,
    float* __restrict__ out, float* __restrict__ amOut,
    int M, int K) {
    __shared__ float As[BK][BM + 4];
    __shared__ float Bs[BK][BN];
    __shared__ float sd[4];
    const float sW = qscale(amW);
    const float sX = qscale(amX);
    const int bm = blockIdx.y * BM;
    const int bn = blockIdx.x * BN;
    const int tid = threadIdx.x;
    const int tx = tid & 15, ty = tid >> 4;
    float acc[4][4] = {};

    for (int k0 = 0; k0 < K; k0 += BK) {
#pragma unroll
        for (int i = 0; i < 4; ++i) {
            int e = tid * 4 + i;
            int m = e >> 4, c = e & 15;
            int gm = bm + m, gk = k0 + c;
            float v = 0.f;
            if (gm < M && gk < K) v = fq1(W[(size_t)gm * K + gk], sW);
            As[c][m] = v;
        }
#pragma unroll
        for (int i = 0; i < 4; ++i) {
            int e = tid + i * 256;
            int c = e >> 6, j = e & 63;
            int gk = k0 + c;
            float v = 0.f;
            if (gk < K) v = fq1(X[(size_t)gk * BATCH_N + bn + j], sX);
            Bs[c][j] = v;
        }
        __syncthreads();
#pragma unroll
        for (int kk = 0; kk < BK; ++kk) {
            float4 a4 = *(const float4*)&As[kk][ty * 4];
            float4 b4 = *(const float4*)&Bs[kk][tx * 4];
            float av[4] = {a4.x, a4.y, a4.z, a4.w};
            float bv[4] = {b4.x, b4.y, b4.z, b4.w};
#pragma unroll
            for (int i = 0; i < 4; ++i)
#pragma unroll
                for (int j = 0; j < 4; ++j)
                    acc[i][j] = fmaf(av[i], bv[j], acc[i][j]);
        }
        __syncthreads();
    }

    float mx = 0.f;
#pragma unroll
    for (int i = 0; i < 4; ++i) {
        int gm = bm + ty * 4 + i;
        if (gm < M) {
#pragma unroll
            for (int j = 0; j < 4; ++j) {
                float v = acc[i][j];
                out[(size_t)gm * BATCH_N + bn + tx * 4 + j] = v;
                mx = fmaxf(mx, fabsf(v));
            }
        }
    }
    block_amax(mx, amOut, sd);
}

// ------------- elementwise passes (in-place safe) -------------

__global__ __launch_bounds__(256) void k_bias(const float* t, const float* amT,
                                              const float* b, const float* amB,
                                              float* u, float* amU) {
    const float sT = qscale(amT), sB = qscale(amB);
    const int i = (blockIdx.x * 256 + threadIdx.x) * 4;
    const int m = i >> 12;
    const float bb = fq1(b[m], sB);
    float4 v = *(const float4*)(t + i);
    float4 r;
    r.x = fq1(v.x, sT) + bb; r.y = fq1(v.y, sT) + bb;
    r.z = fq1(v.z, sT) + bb; r.w = fq1(v.w, sT) + bb;
    *(float4*)(u + i) = r;
    float mx = fmaxf(fmaxf(fabsf(r.x), fabsf(r.y)), fmaxf(fabsf(r.z), fabsf(r.w)));
    __shared__ float sd[4];
    block_amax(mx, amU, sd);
}

__global__ __launch_bounds__(256) void k_add(const float* a, const float* amA,
                                             const float* b, const float* amB,
                                             float* o, float* amO) {
    const float sA = qscale(amA), sB = qscale(amB);
    const int i = (blockIdx.x * 256 + threadIdx.x) * 4;
    float4 va = *(const float4*)(a + i);
    float4 vb = *(const float4*)(b + i);
    float4 r;
    r.x = fq1(va.x, sA) + fq1(vb.x, sB); r.y = fq1(va.y, sA) + fq1(vb.y, sB);
    r.z = fq1(va.z, sA) + fq1(vb.z, sB); r.w = fq1(va.w, sA) + fq1(vb.w, sB);
    *(float4*)(o + i) = r;
    float mx = fmaxf(fmaxf(fabsf(r.x), fabsf(r.y)), fmaxf(fabsf(r.z), fabsf(r.w)));
    __shared__ float sd[4];
    block_amax(mx, amO, sd);
}

__global__ __launch_bounds__(256) void k_mul(const float* a, const float* amA,
                                             const float* b, const float* amB,
                                             float* o, float* amO) {
    const float sA = qscale(amA), sB = qscale(amB);
    const int i = (blockIdx.x * 256 + threadIdx.x) * 4;
    float4 va = *(const float4*)(a + i);
    float4 vb = *(const float4*)(b + i);
    float4 r;
    r.x = fq1(va.x, sA) * fq1(vb.x, sB); r.y = fq1(va.y, sA) * fq1(vb.y, sB);
    r.z = fq1(va.z, sA) * fq1(vb.z, sB); r.w = fq1(va.w, sA) * fq1(vb.w, sB);
    *(float4*)(o + i) = r;
    float mx = fmaxf(fmaxf(fabsf(r.x), fabsf(r.y)), fmaxf(fabsf(r.z), fabsf(r.w)));
    __shared__ float sd[4];
    block_amax(mx, amO, sd);
}

__global__ __launch_bounds__(256) void k_sig(const float* a, const float* amA,
                                             float* o, float* amO) {
    const float sA = qscale(amA);
    const int i = (blockIdx.x * 256 + threadIdx.x) * 4;
    float4 v = *(const float4*)(a + i);
    float4 r;
    r.x = sigm(fq1(v.x, sA)); r.y = sigm(fq1(v.y, sA));
    r.z = sigm(fq1(v.z, sA)); r.w = sigm(fq1(v.w, sA));
    *(float4*)(o + i) = r;
    float mx = fmaxf(fmaxf(fabsf(r.x), fabsf(r.y)), fmaxf(fabsf(r.z), fabsf(r.w)));
    __shared__ float sd[4];
    block_amax(mx, amO, sd);
}

__global__ __launch_bounds__(256) void k_tanh(const float* a, const float* amA,
                                              float* o, float* amO) {
    const float sA = qscale(amA);
    const int i = (blockIdx.x * 256 + threadIdx.x) * 4;
    float4 v = *(const float4*)(a + i);
    float4 r;
    r.x = tanhf(fq1(v.x, sA)); r.y = tanhf(fq1(v.y, sA));
    r.z = tanhf(fq1(v.z, sA)); r.w = tanhf(fq1(v.w, sA));
    *(float4*)(o + i) = r;
    float mx = fmaxf(fmaxf(fabsf(r.x), fabsf(r.y)), fmaxf(fabsf(r.z), fabsf(r.w)));
    __shared__ float sd[4];
    block_amax(mx, amO, sd);
}

__global__ __launch_bounds__(256) void k_relu(const float* a, const float* amA,
                                              float* o, float* amO) {
    const float sA = qscale(amA);
    const int i = (blockIdx.x * 256 + threadIdx.x) * 4;
    float4 v = *(const float4*)(a + i);
    float4 r;
    r.x = fmaxf(0.f, fq1(v.x, sA)); r.y = fmaxf(0.f, fq1(v.y, sA));
    r.z = fmaxf(0.f, fq1(v.z, sA)); r.w = fmaxf(0.f, fq1(v.w, sA));
    *(float4*)(o + i) = r;
    float mx = fmaxf(fmaxf(fabsf(r.x), fabsf(r.y)), fmaxf(fabsf(r.z), fabsf(r.w)));
    __shared__ float sd[4];
    block_amax(mx, amO, sd);
}

__global__ __launch_bounds__(256) void k_omzzh(const float* z, const float* amZ,
                                               const float* h, const float* amH,
                                               float* omz, float* amOmz,
                                               float* zh, float* amZh) {
    const float sZ = qscale(amZ), sH = qscale(amH);
    const int i = (blockIdx.x * 256 + threadIdx.x) * 4;
    float4 zv = *(const float4*)(z + i);
    float4 hv = *(const float4*)(h + i);
    float zq[4] = {fq1(zv.x, sZ), fq1(zv.y, sZ), fq1(zv.z, sZ), fq1(zv.w, sZ)};
    float hq[4] = {fq1(hv.x, sH), fq1(hv.y, sH), fq1(hv.z, sH), fq1(hv.w, sH)};
    float4 o, p;
    o.x = 1.f - zq[0]; o.y = 1.f - zq[1]; o.z = 1.f - zq[2]; o.w = 1.f - zq[3];
    p.x = zq[0] * hq[0]; p.y = zq[1] * hq[1]; p.z = zq[2] * hq[2]; p.w = zq[3] * hq[3];
    *(float4*)(omz + i) = o;
    *(float4*)(zh + i) = p;
    float mo = fmaxf(fmaxf(fabsf(o.x), fabsf(o.y)), fmaxf(fabsf(o.z), fabsf(o.w)));
    float mp = fmaxf(fmaxf(fabsf(p.x), fabsf(p.y)), fmaxf(fabsf(p.z), fabsf(p.w)));
    __shared__ float sd[8];
    block_amax(mo, amOmz, sd);
    block_amax(mp, amZh, sd + 4);
}

// final: out = fq(sigmoid_raw) as FLOAT; health cascade emits distinct constants
__global__ __launch_bounds__(256) void k_out(const float* sg, const float* AMall,
                                             float* out) {
    float c = -1.f;
    if (AMall[120] != MAGIC) c = 3.5f;                 // ws writes don't persist
    else if (!(AMall[0]  > 1e-9f)) c = 10.f;           // input absmax dead
    else if (!(AMall[35] > 1e-9f)) c = 11.f;           // GEMM fused atomic dead
    else if (!(AMall[36] > 1e-9f)) c = 12.f;           // k_bias atomic dead
    else if (!(AMall[59] > 1e-9f)) c = 13.f;           // GRU1 chain dead
    else if (!(AMall[82] > 1e-9f)) c = 14.f;           // GRU2 chain dead
    else if (!(AMall[90] > 1e-9f)) c = 15.f;           // fc4 chain dead
    else if (!(AMall[91] > 1e-6f)) c = 16.f;           // final sigmoid amax dead
    const int i = (blockIdx.x * 256 + threadIdx.x) * 4;
    if (c >= 0.f) {
        out[i] = c; out[i + 1] = c; out[i + 2] = c; out[i + 3] = c;
        return;
    }
    const float s = AMall[91] / 127.0f + 1e-12f;
    float4 v = *(const float4*)(sg + i);
    float4 r;
    r.x = fq1(v.x, s); r.y = fq1(v.y, s); r.z = fq1(v.z, s); r.w = fq1(v.w, s);
    if (!(fabsf(r.x) <= 1.5f)) r.x = 4.5f;             // NaN/garbage probe
    if (!(fabsf(r.y) <= 1.5f)) r.y = 4.5f;
    if (!(fabsf(r.z) <= 1.5f)) r.z = 4.5f;
    if (!(fabsf(r.w) <= 1.5f)) r.w = 4.5f;
    *(float4*)(out + i) = r;
}

// ---------------- host orchestration ----------------
extern "C" void kernel_launch(void* const* d_in, const int* in_sizes, int n_in,
                              void* d_out, int out_size, void* d_ws, size_t ws_size,
                              hipStream_t stream) {
    const float* in[35];
    for (int i = 0; i < 35; ++i) in[i] = (const float*)d_in[i];
    float* fout = (float*)d_out;

    const size_t NEED = (size_t)(128 + 4 * (size_t)R4) * sizeof(float);  // 26.2 MB
    if (ws_size < NEED) {
        k_fill<<<(out_size + 255) / 256, 256, 0, stream>>>(fout, out_size, 0.25f);
        return;
    }

    float* AM = (float*)d_ws;
    float* X  = AM + 128;
    float* A  = X + R4;
    float* B  = A + R4;
    float* C  = B + R4;
    float* F1 = A;
    float* F2 = A + R6;

    k_init<<<1, 128, 0, stream>>>(AM);

    AbsmaxArgs aa;
    for (int i = 0; i < 35; ++i) { aa.p[i] = in[i]; aa.n[i] = in_sizes[i]; }
    aa.am = AM;
    absmax_multi<<<35, 256, 0, stream>>>(aa);

    auto gemm = [&](const float* W, int amW, const float* V, int amV,
                    float* T, int amT, int M, int K) {
        gemm_fq<<<dim3(BATCH_N / BN, (M + BM - 1) / BM), 256, 0, stream>>>(
            W, AM + amW, V, AM + amV, T, AM + amT, M, K);
    };
    auto bias = [&](float* T, int amT, const float* bv, int amB, int amU, int M) {
        k_bias<<<M * 4, 256, 0, stream>>>(T, AM + amT, bv, AM + amB, T, AM + amU);
    };
    auto add = [&](const float* a, int ama, const float* b, int amb, float* o, int amo, int M) {
        k_add<<<M * 4, 256, 0, stream>>>(a, AM + ama, b, AM + amb, o, AM + amo);
    };
    auto mul = [&](const float* a, int ama, const float* b, int amb, float* o, int amo, int M) {
        k_mul<<<M * 4, 256, 0, stream>>>(a, AM + ama, b, AM + amb, o, AM + amo);
    };
    auto sig = [&](float* a, int ama, int amo, int M) {
        k_sig<<<M * 4, 256, 0, stream>>>(a, AM + ama, a, AM + amo);
    };
    auto tnh = [&](float* a, int ama, int amo, int M) {
        k_tanh<<<M * 4, 256, 0, stream>>>(a, AM + ama, a, AM + amo);
    };
    auto relu = [&](float* a, int ama, int amo, int M) {
        k_relu<<<M * 4, 256, 0, stream>>>(a, AM + ama, a, AM + amo);
    };

    // fc1 -> X
    gemm(in[3], 3, in[0], 0, X, 35, 400, 257);
    bias(X, 35, in[4], 4, 36, 400);

    auto gru = [&](int wb, int amXin, const float* h, int amH, int ab) {
        gemm(in[wb + 0], wb + 0, X, amXin, A, ab + 0, 400, 400);   // a
        bias(A, ab + 0, in[wb + 2], wb + 2, ab + 1, 400);
        gemm(in[wb + 1], wb + 1, h, amH, B, ab + 2, 400, 400);     // b
        bias(B, ab + 2, in[wb + 3], wb + 3, ab + 3, 400);
        add(A, ab + 1, B, ab + 3, A, ab + 4, 400);
        sig(A, ab + 4, ab + 5, 400);                               // r in A
        gemm(in[wb + 4], wb + 4, X, amXin, B, ab + 6, 400, 400);   // c
        bias(B, ab + 6, in[wb + 6], wb + 6, ab + 7, 400);
        gemm(in[wb + 5], wb + 5, h, amH, C, ab + 8, 400, 400);     // d
        bias(C, ab + 8, in[wb + 7], wb + 7, ab + 9, 400);
        add(B, ab + 7, C, ab + 9, B, ab + 10, 400);
        sig(B, ab + 10, ab + 11, 400);                             // z in B
        gemm(in[wb + 9], wb + 9, h, amH, C, ab + 12, 400, 400);    // f
        bias(C, ab + 12, in[wb + 11], wb + 11, ab + 13, 400);
        mul(A, ab + 5, C, ab + 13, A, ab + 14, 400);               // rf
        gemm(in[wb + 8], wb + 8, X, amXin, C, ab + 15, 400, 400);  // e (last X use)
        bias(C, ab + 15, in[wb + 10], wb + 10, ab + 16, 400);
        add(C, ab + 16, A, ab + 14, A, ab + 17, 400);              // e + fq(rf)
        tnh(A, ab + 17, ab + 18, 400);                             // tn in A
        k_omzzh<<<400 * 4, 256, 0, stream>>>(B, AM + ab + 11, h, AM + amH,
                                             C, AM + ab + 19, X, AM + ab + 20);
        mul(C, ab + 19, A, ab + 18, A, ab + 21, 400);              // t2
        add(A, ab + 21, X, ab + 20, X, ab + 22, 400);              // g -> X
    };

    gru(5, 36, in[1], 1, 37);      // g1 am 59
    gru(17, 59, in[2], 2, 60);     // g2 am 82

    gemm(in[29], 29, X, 82, F1, 83, 600, 400);
    bias(F1, 83, in[30], 30, 84, 600);
    relu(F1, 84, 85, 600);
    gemm(in[31], 31, F1, 85, F2, 86, 600, 600);
    bias(F2, 86, in[32], 32, 87, 600);
    relu(F2, 87, 88, 600);
    gemm(in[33], 33, F2, 88, X, 89, 257, 600);
    bias(X, 89, in[34], 34, 90, 257);
    sig(X, 90, 91, 257);
    k_out<<<257 * 4, 256, 0, stream>>>(X, AM, fout);

    (void)n_in; (void)ws_size; (void)in_sizes;
}

// Round 7
// 2053.260 us; speedup vs baseline: 1.1521x; 1.1521x over previous
//
#include <hip/hip_runtime.h>

// Q_NsNet2: fake-quantized FC + 2xGRU + FC stack. Output f32.
// ROUND 7: bit-identical reproduction of round-5 numerics (the proven PASS at
// absmax 0.015625), optimized:
//   - absmax_multi: multi-block + atomicMax (max is order-invariant -> exact)
//   - weights pre-dequantized once (k_dqw) -> removes redundant IEEE divides
//     from GEMM A-side; staged values bitwise identical to round-5's in-GEMM fq1
//   - GEMM BK 16->32: per-output fmaf chain remains ascending-k -> bit-identical
// Workspace (floats): AM[128] | X,A,B,C (4x R4) | Wd[1,062,800] = 30.47 MB

#define BATCH_N 4096
#define R4 (400 * 4096)
#define R6 (600 * 4096)
#define MAGIC 123.0f
#define WD_ELEMS 1062800

__device__ __forceinline__ float qscale(const float* am) { return am[0] / 127.0f + 1e-12f; }

__device__ __forceinline__ float fq1(float x, float s) {
    float q = rintf(x / s);                    // round-half-even, IEEE divide
    q = fminf(fmaxf(q, -127.0f), 127.0f);
    return q * s;
}

__device__ __forceinline__ float sigm(float x) {
    if (x >= 0.f) { float e = expf(-x); return 1.0f / (1.0f + e); }
    float e = expf(x); return e / (1.0f + e);
}

__device__ __forceinline__ float wave_max64(float v) {
#pragma unroll
    for (int off = 32; off > 0; off >>= 1)
        v = fmaxf(v, __shfl_down(v, off, 64));
    return v;
}

// Block-wide absmax -> one atomicMax per block (float-as-uint: exact for >=0).
__device__ __forceinline__ void block_amax(float v, float* slot, float* sd) {
    v = wave_max64(v);
    int lane = threadIdx.x & 63, w = threadIdx.x >> 6;
    if (lane == 0) sd[w] = v;
    __syncthreads();
    if (threadIdx.x == 0) {
        int nw = blockDim.x >> 6;
        float m = sd[0];
        for (int i = 1; i < nw; ++i) m = fmaxf(m, sd[i]);
        atomicMax((unsigned int*)slot, __float_as_uint(m));
    }
}

__global__ void k_init(float* am) {
    int t = threadIdx.x;
    if (t < 128) am[t] = (t == 120) ? MAGIC : 0.f;
}

__global__ void k_fill(float* out, int n, float c) {   // ws-too-small diagnostic
    int i = blockIdx.x * 256 + threadIdx.x;
    if (i < n) out[i] = c;
}

// ---- input absmax: multi-block per tensor + atomicMax (AM pre-zeroed) ----
struct AbsmaxArgs {
    const float* p[35];
    int n[35];
    float* am;
};

__global__ __launch_bounds__(256) void absmax_multi(AbsmaxArgs a) {
    int t = blockIdx.y;
    const float* p = a.p[t];
    int n = a.n[t];
    int nv = n >> 2;
    float v = 0.f;
    for (int i = blockIdx.x * 256 + threadIdx.x; i < nv; i += gridDim.x * 256) {
        float4 x = *(const float4*)(p + (size_t)i * 4);
        v = fmaxf(v, fmaxf(fmaxf(fabsf(x.x), fabsf(x.y)), fmaxf(fabsf(x.z), fabsf(x.w))));
    }
    for (int i = nv * 4 + blockIdx.x * 256 + threadIdx.x; i < n; i += gridDim.x * 256)
        v = fmaxf(v, fabsf(p[i]));
    __shared__ float sd[4];
    block_amax(v, a.am + t, sd);
}

// ---- batched weight dequant: Wd[i] = fq1(W[i], sW) (bitwise == in-GEMM fq1) ----
struct DqwArgs {
    const float* src[8];
    int off[8], n[8], amIdx[8];
};

__global__ __launch_bounds__(256) void k_dqw(DqwArgs a, float* wd, const float* AM) {
    int t = blockIdx.y;
    const float s = AM[a.amIdx[t]] / 127.0f + 1e-12f;
    const float* src = a.src[t];
    float* dst = wd + a.off[t];
    int n = a.n[t];
    for (int i = blockIdx.x * 256 + threadIdx.x; i < n; i += gridDim.x * 256)
        dst[i] = fq1(src[i], s);
}

// ---- GEMM: out = Wd @ fq(X), fused absmax. Bit-identical to round-5 gemm_fq:
// same staged values, same ascending-k fmaf order per output. ----
#define BM 64
#define BN 64
#define BK 32

__global__ __launch_bounds__(256) void gemm_f32(
    const float* __restrict__ Wd, const float* __restrict__ X,
    const float* __restrict__ amX,
    float* __restrict__ out, float* __restrict__ amOut,
    int M, int K) {
    __shared__ float As[BK][BM + 4];
    __shared__ float Bs[BK][BN];
    __shared__ float sd[4];
    const float sX = qscale(amX);
    const int bm = blockIdx.y * BM, bn = blockIdx.x * BN;
    const int tid = threadIdx.x;
    const int tx = tid & 15, ty = tid >> 4;
    const int am_ = tid >> 2, ac0 = (tid & 3) * 8;
    float acc[4][4] = {};

    for (int k0 = 0; k0 < K; k0 += BK) {
        {   // A tile 64x32 from pre-dequantized Wd
            int gm = bm + am_;
#pragma unroll
            for (int j = 0; j < 8; ++j) {
                int gk = k0 + ac0 + j;
                float v = 0.f;
                if (gm < M && gk < K) v = Wd[(size_t)gm * K + gk];
                As[ac0 + j][am_] = v;
            }
        }
#pragma unroll
        for (int i = 0; i < 8; ++i) {   // B tile 32x64, fq on load (round-5 path)
            int e = i * 256 + tid;
            int c = e >> 6, j = e & 63;
            int gk = k0 + c;
            float v = 0.f;
            if (gk < K) v = fq1(X[(size_t)gk * BATCH_N + bn + j], sX);
            Bs[c][j] = v;
        }
        __syncthreads();
#pragma unroll
        for (int kk = 0; kk < BK; ++kk) {
            float4 a4 = *(const float4*)&As[kk][ty * 4];
            float4 b4 = *(const float4*)&Bs[kk][tx * 4];
            float av[4] = {a4.x, a4.y, a4.z, a4.w};
            float bv[4] = {b4.x, b4.y, b4.z, b4.w};
#pragma unroll
            for (int i2 = 0; i2 < 4; ++i2)
#pragma unroll
                for (int j2 = 0; j2 < 4; ++j2)
                    acc[i2][j2] = fmaf(av[i2], bv[j2], acc[i2][j2]);
        }
        __syncthreads();
    }

    float mx = 0.f;
#pragma unroll
    for (int i = 0; i < 4; ++i) {
        int gm = bm + ty * 4 + i;
        if (gm < M) {
#pragma unroll
            for (int j = 0; j < 4; ++j) {
                float v = acc[i][j];
                out[(size_t)gm * BATCH_N + bn + tx * 4 + j] = v;
                mx = fmaxf(mx, fabsf(v));
            }
        }
    }
    block_amax(mx, amOut, sd);
}

// ------------- elementwise passes (verbatim round 5, in-place safe) -------------

__global__ __launch_bounds__(256) void k_bias(const float* t, const float* amT,
                                              const float* b, const float* amB,
                                              float* u, float* amU) {
    const float sT = qscale(amT), sB = qscale(amB);
    const int i = (blockIdx.x * 256 + threadIdx.x) * 4;
    const int m = i >> 12;
    const float bb = fq1(b[m], sB);
    float4 v = *(const float4*)(t + i);
    float4 r;
    r.x = fq1(v.x, sT) + bb; r.y = fq1(v.y, sT) + bb;
    r.z = fq1(v.z, sT) + bb; r.w = fq1(v.w, sT) + bb;
    *(float4*)(u + i) = r;
    float mx = fmaxf(fmaxf(fabsf(r.x), fabsf(r.y)), fmaxf(fabsf(r.z), fabsf(r.w)));
    __shared__ float sd[4];
    block_amax(mx, amU, sd);
}

__global__ __launch_bounds__(256) void k_add(const float* a, const float* amA,
                                             const float* b, const float* amB,
                                             float* o, float* amO) {
    const float sA = qscale(amA), sB = qscale(amB);
    const int i = (blockIdx.x * 256 + threadIdx.x) * 4;
    float4 va = *(const float4*)(a + i);
    float4 vb = *(const float4*)(b + i);
    float4 r;
    r.x = fq1(va.x, sA) + fq1(vb.x, sB); r.y = fq1(va.y, sA) + fq1(vb.y, sB);
    r.z = fq1(va.z, sA) + fq1(vb.z, sB); r.w = fq1(va.w, sA) + fq1(vb.w, sB);
    *(float4*)(o + i) = r;
    float mx = fmaxf(fmaxf(fabsf(r.x), fabsf(r.y)), fmaxf(fabsf(r.z), fabsf(r.w)));
    __shared__ float sd[4];
    block_amax(mx, amO, sd);
}

__global__ __launch_bounds__(256) void k_mul(const float* a, const float* amA,
                                             const float* b, const float* amB,
                                             float* o, float* amO) {
    const float sA = qscale(amA), sB = qscale(amB);
    const int i = (blockIdx.x * 256 + threadIdx.x) * 4;
    float4 va = *(const float4*)(a + i);
    float4 vb = *(const float4*)(b + i);
    float4 r;
    r.x = fq1(va.x, sA) * fq1(vb.x, sB); r.y = fq1(va.y, sA) * fq1(vb.y, sB);
    r.z = fq1(va.z, sA) * fq1(vb.z, sB); r.w = fq1(va.w, sA) * fq1(vb.w, sB);
    *(float4*)(o + i) = r;
    float mx = fmaxf(fmaxf(fabsf(r.x), fabsf(r.y)), fmaxf(fabsf(r.z), fabsf(r.w)));
    __shared__ float sd[4];
    block_amax(mx, amO, sd);
}

__global__ __launch_bounds__(256) void k_sig(const float* a, const float* amA,
                                             float* o, float* amO) {
    const float sA = qscale(amA);
    const int i = (blockIdx.x * 256 + threadIdx.x) * 4;
    float4 v = *(const float4*)(a + i);
    float4 r;
    r.x = sigm(fq1(v.x, sA)); r.y = sigm(fq1(v.y, sA));
    r.z = sigm(fq1(v.z, sA)); r.w = sigm(fq1(v.w, sA));
    *(float4*)(o + i) = r;
    float mx = fmaxf(fmaxf(fabsf(r.x), fabsf(r.y)), fmaxf(fabsf(r.z), fabsf(r.w)));
    __shared__ float sd[4];
    block_amax(mx, amO, sd);
}

__global__ __launch_bounds__(256) void k_tanh(const float* a, const float* amA,
                                              float* o, float* amO) {
    const float sA = qscale(amA);
    const int i = (blockIdx.x * 256 + threadIdx.x) * 4;
    float4 v = *(const float4*)(a + i);
    float4 r;
    r.x = tanhf(fq1(v.x, sA)); r.y = tanhf(fq1(v.y, sA));
    r.z = tanhf(fq1(v.z, sA)); r.w = tanhf(fq1(v.w, sA));
    *(float4*)(o + i) = r;
    float mx = fmaxf(fmaxf(fabsf(r.x), fabsf(r.y)), fmaxf(fabsf(r.z), fabsf(r.w)));
    __shared__ float sd[4];
    block_amax(mx, amO, sd);
}

__global__ __launch_bounds__(256) void k_relu(const float* a, const float* amA,
                                              float* o, float* amO) {
    const float sA = qscale(amA);
    const int i = (blockIdx.x * 256 + threadIdx.x) * 4;
    float4 v = *(const float4*)(a + i);
    float4 r;
    r.x = fmaxf(0.f, fq1(v.x, sA)); r.y = fmaxf(0.f, fq1(v.y, sA));
    r.z = fmaxf(0.f, fq1(v.z, sA)); r.w = fmaxf(0.f, fq1(v.w, sA));
    *(float4*)(o + i) = r;
    float mx = fmaxf(fmaxf(fabsf(r.x), fabsf(r.y)), fmaxf(fabsf(r.z), fabsf(r.w)));
    __shared__ float sd[4];
    block_amax(mx, amO, sd);
}

__global__ __launch_bounds__(256) void k_omzzh(const float* z, const float* amZ,
                                               const float* h, const float* amH,
                                               float* omz, float* amOmz,
                                               float* zh, float* amZh) {
    const float sZ = qscale(amZ), sH = qscale(amH);
    const int i = (blockIdx.x * 256 + threadIdx.x) * 4;
    float4 zv = *(const float4*)(z + i);
    float4 hv = *(const float4*)(h + i);
    float zq[4] = {fq1(zv.x, sZ), fq1(zv.y, sZ), fq1(zv.z, sZ), fq1(zv.w, sZ)};
    float hq[4] = {fq1(hv.x, sH), fq1(hv.y, sH), fq1(hv.z, sH), fq1(hv.w, sH)};
    float4 o, p;
    o.x = 1.f - zq[0]; o.y = 1.f - zq[1]; o.z = 1.f - zq[2]; o.w = 1.f - zq[3];
    p.x = zq[0] * hq[0]; p.y = zq[1] * hq[1]; p.z = zq[2] * hq[2]; p.w = zq[3] * hq[3];
    *(float4*)(omz + i) = o;
    *(float4*)(zh + i) = p;
    float mo = fmaxf(fmaxf(fabsf(o.x), fabsf(o.y)), fmaxf(fabsf(o.z), fabsf(o.w)));
    float mp = fmaxf(fmaxf(fabsf(p.x), fabsf(p.y)), fmaxf(fabsf(p.z), fabsf(p.w)));
    __shared__ float sd[8];
    block_amax(mo, amOmz, sd);
    block_amax(mp, amZh, sd + 4);
}

__global__ __launch_bounds__(256) void k_out(const float* sg, const float* AMall,
                                             float* out) {
    float c = -1.f;
    if (AMall[120] != MAGIC) c = 3.5f;
    else if (!(AMall[0]  > 1e-9f)) c = 10.f;
    else if (!(AMall[35] > 1e-9f)) c = 11.f;
    else if (!(AMall[36] > 1e-9f)) c = 12.f;
    else if (!(AMall[59] > 1e-9f)) c = 13.f;
    else if (!(AMall[82] > 1e-9f)) c = 14.f;
    else if (!(AMall[90] > 1e-9f)) c = 15.f;
    else if (!(AMall[91] > 1e-6f)) c = 16.f;
    const int i = (blockIdx.x * 256 + threadIdx.x) * 4;
    if (c >= 0.f) {
        out[i] = c; out[i + 1] = c; out[i + 2] = c; out[i + 3] = c;
        return;
    }
    const float s = AMall[91] / 127.0f + 1e-12f;
    float4 v = *(const float4*)(sg + i);
    float4 r;
    r.x = fq1(v.x, s); r.y = fq1(v.y, s); r.z = fq1(v.z, s); r.w = fq1(v.w, s);
    if (!(fabsf(r.x) <= 1.5f)) r.x = 4.5f;
    if (!(fabsf(r.y) <= 1.5f)) r.y = 4.5f;
    if (!(fabsf(r.z) <= 1.5f)) r.z = 4.5f;
    if (!(fabsf(r.w) <= 1.5f)) r.w = 4.5f;
    *(float4*)(out + i) = r;
}

// ---------------- host orchestration ----------------
extern "C" void kernel_launch(void* const* d_in, const int* in_sizes, int n_in,
                              void* d_out, int out_size, void* d_ws, size_t ws_size,
                              hipStream_t stream) {
    const float* in[35];
    for (int i = 0; i < 35; ++i) in[i] = (const float*)d_in[i];
    float* fout = (float*)d_out;

    const size_t NEED = (size_t)(128 + 4 * (size_t)R4 + WD_ELEMS) * 4;  // 30.47 MB
    if (ws_size < NEED) {
        k_fill<<<(out_size + 255) / 256, 256, 0, stream>>>(fout, out_size, 0.25f);
        return;
    }

    float* AM = (float*)d_ws;
    float* X  = AM + 128;
    float* A  = X + R4;
    float* B  = A + R4;
    float* C  = B + R4;
    float* F1 = A;                    // 600-row views (3*R4 == 2*R6)
    float* F2 = A + R6;
    float* Wd = C + R4;               // WD_ELEMS floats

    // Wd offsets (floats): fc1 @0; 6 GRU slots @102800+i*160000 (reused by both
    // GRUs); FC phase reuses @102800.
    const int GOF[6] = {102800, 262800, 422800, 582800, 742800, 902800};

    k_init<<<1, 128, 0, stream>>>(AM);

    AbsmaxArgs aa;
    for (int i = 0; i < 35; ++i) { aa.p[i] = in[i]; aa.n[i] = in_sizes[i]; }
    aa.am = AM;
    absmax_multi<<<dim3(16, 35), 256, 0, stream>>>(aa);

    auto dqw = [&](const int* ins, const int* offs, const int* ns, int cnt) {
        DqwArgs d{};
        for (int i = 0; i < cnt; ++i) {
            d.src[i] = in[ins[i]]; d.off[i] = offs[i]; d.n[i] = ns[i]; d.amIdx[i] = ins[i];
        }
        k_dqw<<<dim3(64, cnt), 256, 0, stream>>>(d, Wd, AM);
    };
    auto gemm = [&](int wdOff, const float* Xp, int amX, float* T, int amT, int M, int K) {
        gemm_f32<<<dim3(BATCH_N / BN, (M + BM - 1) / BM), 256, 0, stream>>>(
            Wd + wdOff, Xp, AM + amX, T, AM + amT, M, K);
    };
    auto bias = [&](float* T, int amT, const float* bv, int amB, int amU, int M) {
        k_bias<<<M * 4, 256, 0, stream>>>(T, AM + amT, bv, AM + amB, T, AM + amU);
    };
    auto add = [&](const float* a, int ama, const float* b, int amb, float* o, int amo, int M) {
        k_add<<<M * 4, 256, 0, stream>>>(a, AM + ama, b, AM + amb, o, AM + amo);
    };
    auto mul = [&](const float* a, int ama, const float* b, int amb, float* o, int amo, int M) {
        k_mul<<<M * 4, 256, 0, stream>>>(a, AM + ama, b, AM + amb, o, AM + amo);
    };
    auto sig = [&](float* a, int ama, int amo, int M) {
        k_sig<<<M * 4, 256, 0, stream>>>(a, AM + ama, a, AM + amo);
    };
    auto tnh = [&](float* a, int ama, int amo, int M) {
        k_tanh<<<M * 4, 256, 0, stream>>>(a, AM + ama, a, AM + amo);
    };
    auto relu = [&](float* a, int ama, int amo, int M) {
        k_relu<<<M * 4, 256, 0, stream>>>(a, AM + ama, a, AM + amo);
    };

    // dequant batch 1: fc1 W + GRU1 weights
    {
        const int ins[7]  = {3, 5, 6, 9, 10, 13, 14};
        const int offs[7] = {0, GOF[0], GOF[1], GOF[2], GOF[3], GOF[4], GOF[5]};
        const int ns[7]   = {102800, 160000, 160000, 160000, 160000, 160000, 160000};
        dqw(ins, offs, ns, 7);
    }

    // fc1 -> X (t am35, u am36) — B-operand = raw input x with fq-on-load
    gemm(0, in[0], 0, X, 35, 400, 257);
    bias(X, 35, in[4], 4, 36, 400);

    // GRU (round-5 wiring verbatim; xin and g live in X)
    auto gru = [&](int wb, int amXin, const float* h, int amH, int ab) {
        gemm(GOF[0], X, amXin, A, ab + 0, 400, 400);               // a
        bias(A, ab + 0, in[wb + 2], wb + 2, ab + 1, 400);
        gemm(GOF[1], h, amH, B, ab + 2, 400, 400);                 // b
        bias(B, ab + 2, in[wb + 3], wb + 3, ab + 3, 400);
        add(A, ab + 1, B, ab + 3, A, ab + 4, 400);
        sig(A, ab + 4, ab + 5, 400);                               // r in A
        gemm(GOF[2], X, amXin, B, ab + 6, 400, 400);               // c
        bias(B, ab + 6, in[wb + 6], wb + 6, ab + 7, 400);
        gemm(GOF[3], h, amH, C, ab + 8, 400, 400);                 // d
        bias(C, ab + 8, in[wb + 7], wb + 7, ab + 9, 400);
        add(B, ab + 7, C, ab + 9, B, ab + 10, 400);
        sig(B, ab + 10, ab + 11, 400);                             // z in B
        gemm(GOF[5], h, amH, C, ab + 12, 400, 400);                // f
        bias(C, ab + 12, in[wb + 11], wb + 11, ab + 13, 400);
        mul(A, ab + 5, C, ab + 13, A, ab + 14, 400);               // rf
        gemm(GOF[4], X, amXin, C, ab + 15, 400, 400);              // e (last X use)
        bias(C, ab + 15, in[wb + 10], wb + 10, ab + 16, 400);
        add(C, ab + 16, A, ab + 14, A, ab + 17, 400);              // e + fq(rf)
        tnh(A, ab + 17, ab + 18, 400);                             // tn in A
        k_omzzh<<<400 * 4, 256, 0, stream>>>(B, AM + ab + 11, h, AM + amH,
                                             C, AM + ab + 19, X, AM + ab + 20);
        mul(C, ab + 19, A, ab + 18, A, ab + 21, 400);              // t2
        add(A, ab + 21, X, ab + 20, X, ab + 22, 400);              // g -> X
    };

    gru(5, 36, in[1], 1, 37);      // g1 am 59

    // dequant batch 2: GRU2 weights (after GRU1's gemms in stream order)
    {
        const int ins[6]  = {17, 18, 21, 22, 25, 26};
        const int offs[6] = {GOF[0], GOF[1], GOF[2], GOF[3], GOF[4], GOF[5]};
        const int ns[6]   = {160000, 160000, 160000, 160000, 160000, 160000};
        dqw(ins, offs, ns, 6);
    }
    gru(17, 59, in[2], 2, 60);     // g2 am 82

    // dequant batch 3: FC weights
    {
        const int ins[3]  = {29, 31, 33};
        const int offs[3] = {102800, 342800, 702800};
        const int ns[3]   = {240000, 360000, 154200};
        dqw(ins, offs, ns, 3);
    }

    gemm(102800, X, 82, F1, 83, 600, 400);
    bias(F1, 83, in[30], 30, 84, 600);
    relu(F1, 84, 85, 600);
    gemm(342800, F1, 85, F2, 86, 600, 600);
    bias(F2, 86, in[32], 32, 87, 600);
    relu(F2, 87, 88, 600);
    gemm(702800, F2, 88, X, 89, 257, 600);
    bias(X, 89, in[34], 34, 90, 257);
    sig(X, 90, 91, 257);
    k_out<<<257 * 4, 256, 0, stream>>>(X, AM, fout);

    (void)n_in; (void)ws_size; (void)in_sizes;
}

// Round 9
// 2052.140 us; speedup vs baseline: 1.1527x; 1.0005x over previous
//
#include <hip/hip_runtime.h>

// Q_NsNet2: fake-quantized FC + 2xGRU + FC stack. Output f32.
// ROUND 9 (= round-8 resubmit; container failure, kernel never ran).
// Bit-identical to round-5/7 numerics (proven PASS, absmax 0.015625).
//  - merged GRU GEMMs (3 weight mats stacked -> M=1200) for occupancy
//  - activations pre-fq'd in place (fq1 idempotent bitwise) -> staging = pure loads
//  - weights dequantized into padded arena (Kp mult 32; zero pad => fmaf(0,.) = acc)
//  - per-wave atomicMax epilogue (max is order-invariant)
// Layouts: MID (proven 30.2 MB): X,A,B,C + arena. BIG (43.3 MB, runtime-gated):
// X,A,B,C,D,E + arena -> h-side also merged.

#define BATCH_N 4096
#define R4 (400 * 4096)
#define R6 (600 * 4096)
#define MAGIC 123.0f
#define ARENA_F 998400          // floats: 2x 1200x416 stacks

__device__ __forceinline__ float qscale(const float* am) { return am[0] / 127.0f + 1e-12f; }
__device__ __forceinline__ float qscale_v(float amv) { return amv / 127.0f + 1e-12f; }

__device__ __forceinline__ float fq1(float x, float s) {
    float q = rintf(x / s);                    // round-half-even, IEEE divide
    q = fminf(fmaxf(q, -127.0f), 127.0f);
    return q * s;
}

__device__ __forceinline__ float sigm(float x) {
    if (x >= 0.f) { float e = expf(-x); return 1.0f / (1.0f + e); }
    float e = expf(x); return e / (1.0f + e);
}

__device__ __forceinline__ float wave_max64(float v) {
#pragma unroll
    for (int off = 32; off > 0; off >>= 1)
        v = fmaxf(v, __shfl_down(v, off, 64));
    return v;
}

__device__ __forceinline__ void block_amax(float v, float* slot, float* sd) {
    v = wave_max64(v);
    int lane = threadIdx.x & 63, w = threadIdx.x >> 6;
    if (lane == 0) sd[w] = v;
    __syncthreads();
    if (threadIdx.x == 0) {
        int nw = blockDim.x >> 6;
        float m = sd[0];
        for (int i = 1; i < nw; ++i) m = fmaxf(m, sd[i]);
        atomicMax((unsigned int*)slot, __float_as_uint(m));
    }
}

__global__ void k_init(float* am) {
    int t = threadIdx.x;
    if (t < 128) am[t] = (t == 120) ? MAGIC : 0.f;
}

__global__ void k_fill(float* out, int n, float c) {
    int i = blockIdx.x * 256 + threadIdx.x;
    if (i < n) out[i] = c;
}

// ---- input absmax ----
struct AbsmaxArgs { const float* p[35]; int n[35]; float* am; };

__global__ __launch_bounds__(256) void absmax_multi(AbsmaxArgs a) {
    int t = blockIdx.y;
    const float* p = a.p[t];
    int n = a.n[t];
    int nv = n >> 2;
    float v = 0.f;
    for (int i = blockIdx.x * 256 + threadIdx.x; i < nv; i += gridDim.x * 256) {
        float4 x = *(const float4*)(p + (size_t)i * 4);
        v = fmaxf(v, fmaxf(fmaxf(fabsf(x.x), fabsf(x.y)), fmaxf(fabsf(x.z), fabsf(x.w))));
    }
    for (int i = nv * 4 + blockIdx.x * 256 + threadIdx.x; i < n; i += gridDim.x * 256)
        v = fmaxf(v, fabsf(p[i]));
    __shared__ float sd[4];
    block_amax(v, a.am + t, sd);
}

// ---- weight dequant into padded arena: wd[m][k<K]=fq1(src), pad=0 ----
struct DqwArgs { const float* src[8]; int off[8], M[8], K[8], Kp[8], amIdx[8]; };

__global__ __launch_bounds__(256) void k_dqw(DqwArgs a, float* wd, const float* AM) {
    int t = blockIdx.y;
    const float s = qscale_v(AM[a.amIdx[t]]);
    const float* src = a.src[t];
    float* dst = wd + a.off[t];
    int K = a.K[t], Kp = a.Kp[t], MK = a.M[t] * Kp;
    for (int e = blockIdx.x * 256 + threadIdx.x; e < MK; e += gridDim.x * 256) {
        int m = e / Kp, k = e - m * Kp;
        dst[e] = (k < K) ? fq1(src[(size_t)m * K + k], s) : 0.f;
    }
}

// ---- in-place activation fq (bitwise idempotent vs consumer-side fq1) ----
__global__ __launch_bounds__(256) void k_dqa(float* x, const float* am) {
    const float s = qscale(am);
    const int i = (blockIdx.x * 256 + threadIdx.x) * 4;
    float4 v = *(const float4*)(x + i);
    v.x = fq1(v.x, s); v.y = fq1(v.y, s); v.z = fq1(v.z, s); v.w = fq1(v.w, s);
    *(float4*)(x + i) = v;
}

// ---- GEMM: out = Wd(padded, pre-fq) @ B, fused segmented absmax.
// TM rows x 4 cols per thread; BM=16*TM, BN=64, BK=32; 256 threads.
// FQB: apply fq1 to B on staging (raw-input operands) or pure load (pre-fq'd).
template<int TM, bool FQB>
__global__ __launch_bounds__(256) void gemm_k(
    const float* __restrict__ Wd, const float* __restrict__ Bop,
    const float* __restrict__ amB,
    float* __restrict__ o0, float* __restrict__ o1, float* __restrict__ o2,
    float* __restrict__ a0, float* __restrict__ a1, float* __restrict__ a2,
    int M, int K, int Kp, int seg_rows, int nseg) {
    constexpr int BM = 16 * TM;
    __shared__ float As[32][BM + 4];
    __shared__ float Bs[32][64];
    float sB = 0.f;
    if (FQB) sB = qscale(amB);
    const int bm = blockIdx.y * BM, bn = blockIdx.x * 64;
    const int tid = threadIdx.x;
    const int tx = tid & 15, ty = tid >> 4;
    float acc[TM][4] = {};

    for (int k0 = 0; k0 < Kp; k0 += 32) {
#pragma unroll
        for (int j = 0; j < TM / 2; ++j) {       // A: BM x 32, padded & aligned
            int q = j * 256 + tid;
            int m = q >> 3, kq = q & 7;
            int gm = bm + m;
            float4 v = make_float4(0.f, 0.f, 0.f, 0.f);
            if (gm < M) v = *(const float4*)(Wd + (size_t)gm * Kp + k0 + kq * 4);
            As[kq * 4 + 0][m] = v.x;
            As[kq * 4 + 1][m] = v.y;
            As[kq * 4 + 2][m] = v.z;
            As[kq * 4 + 3][m] = v.w;
        }
#pragma unroll
        for (int i = 0; i < 8; ++i) {            // B: 32 x 64, coalesced
            int e = i * 256 + tid;
            int c = e >> 6, j2 = e & 63;
            int gk = k0 + c;
            float v = 0.f;
            if (gk < K) {
                v = Bop[(size_t)gk * BATCH_N + bn + j2];
                if (FQB) v = fq1(v, sB);
            }
            Bs[c][j2] = v;
        }
        __syncthreads();
#pragma unroll
        for (int kk = 0; kk < 32; ++kk) {
            float4 b4 = *(const float4*)&Bs[kk][tx * 4];
            float bv[4] = {b4.x, b4.y, b4.z, b4.w};
            float av[TM];
#pragma unroll
            for (int i2 = 0; i2 < TM; ++i2) av[i2] = As[kk][ty * TM + i2];
#pragma unroll
            for (int i2 = 0; i2 < TM; ++i2)
#pragma unroll
                for (int j2 = 0; j2 < 4; ++j2)
                    acc[i2][j2] = fmaf(av[i2], bv[j2], acc[i2][j2]);
        }
        __syncthreads();
    }

    // epilogue: segment by rows (wave-uniform: seg_rows % 16 == 0 or clamped)
    int gm0 = bm + ty * TM;
    int seg = gm0 / seg_rows;
    if (seg > nseg - 1) seg = nseg - 1;
    float* outp = (seg == 0) ? o0 : ((seg == 1) ? o1 : o2);
    float* amp  = (seg == 0) ? a0 : ((seg == 1) ? a1 : a2);
    int lrow0 = gm0 - seg * seg_rows;
    float mx = 0.f;
#pragma unroll
    for (int i = 0; i < TM; ++i) {
        if (gm0 + i < M) {
            float4 r;
            r.x = acc[i][0]; r.y = acc[i][1]; r.z = acc[i][2]; r.w = acc[i][3];
            *(float4*)(outp + (size_t)(lrow0 + i) * BATCH_N + bn + tx * 4) = r;
            mx = fmaxf(mx, fmaxf(fmaxf(fabsf(r.x), fabsf(r.y)), fmaxf(fabsf(r.z), fabsf(r.w))));
        }
    }
    mx = wave_max64(mx);
    if ((tid & 63) == 0) atomicMax((unsigned int*)amp, __float_as_uint(mx));
}

// ------------- elementwise passes (round-5 proven numerics) -------------

__global__ __launch_bounds__(256) void k_bias(const float* t, const float* amT,
                                              const float* b, const float* amB,
                                              float* u, float* amU) {
    const float sT = qscale(amT), sB = qscale(amB);
    const int i = (blockIdx.x * 256 + threadIdx.x) * 4;
    const int m = i >> 12;
    const float bb = fq1(b[m], sB);
    float4 v = *(const float4*)(t + i);
    float4 r;
    r.x = fq1(v.x, sT) + bb; r.y = fq1(v.y, sT) + bb;
    r.z = fq1(v.z, sT) + bb; r.w = fq1(v.w, sT) + bb;
    *(float4*)(u + i) = r;
    float mx = fmaxf(fmaxf(fabsf(r.x), fabsf(r.y)), fmaxf(fabsf(r.z), fabsf(r.w)));
    __shared__ float sd[4];
    block_amax(mx, amU, sd);
}

// 3-tensor bias over stacked row space [3*400][4096]; per-seg ptrs/slots
struct Bias3Args { float* t[3]; const float* bias[3]; int amT[3], amB[3], amU[3]; };

__global__ __launch_bounds__(256) void k_bias3(Bias3Args a, float* AM) {
    const int i = (blockIdx.x * 256 + threadIdx.x) * 4;
    const int row = i >> 12;
    const int seg = row / 400;                   // GRU segs are 400 rows
    const int lrow = row - seg * 400;
    const float sT = qscale_v(AM[a.amT[seg]]);
    const float sB = qscale_v(AM[a.amB[seg]]);
    const float bb = fq1(a.bias[seg][lrow], sB);
    float* t = a.t[seg] + (size_t)lrow * BATCH_N + (i & 4095);
    float4 v = *(const float4*)t;
    float4 r;
    r.x = fq1(v.x, sT) + bb; r.y = fq1(v.y, sT) + bb;
    r.z = fq1(v.z, sT) + bb; r.w = fq1(v.w, sT) + bb;
    *(float4*)t = r;
    float mx = fmaxf(fmaxf(fabsf(r.x), fabsf(r.y)), fmaxf(fabsf(r.z), fabsf(r.w)));
    __shared__ float sd[4];
    block_amax(mx, AM + a.amU[seg], sd);
}

__global__ __launch_bounds__(256) void k_add(const float* a, const float* amA,
                                             const float* b, const float* amB,
                                             float* o, float* amO) {
    const float sA = qscale(amA), sB = qscale(amB);
    const int i = (blockIdx.x * 256 + threadIdx.x) * 4;
    float4 va = *(const float4*)(a + i);
    float4 vb = *(const float4*)(b + i);
    float4 r;
    r.x = fq1(va.x, sA) + fq1(vb.x, sB); r.y = fq1(va.y, sA) + fq1(vb.y, sB);
    r.z = fq1(va.z, sA) + fq1(vb.z, sB); r.w = fq1(va.w, sA) + fq1(vb.w, sB);
    *(float4*)(o + i) = r;
    float mx = fmaxf(fmaxf(fabsf(r.x), fabsf(r.y)), fmaxf(fabsf(r.z), fabsf(r.w)));
    __shared__ float sd[4];
    block_amax(mx, amO, sd);
}

__global__ __launch_bounds__(256) void k_mul(const float* a, const float* amA,
                                             const float* b, const float* amB,
                                             float* o, float* amO) {
    const float sA = qscale(amA), sB = qscale(amB);
    const int i = (blockIdx.x * 256 + threadIdx.x) * 4;
    float4 va = *(const float4*)(a + i);
    float4 vb = *(const float4*)(b + i);
    float4 r;
    r.x = fq1(va.x, sA) * fq1(vb.x, sB); r.y = fq1(va.y, sA) * fq1(vb.y, sB);
    r.z = fq1(va.z, sA) * fq1(vb.z, sB); r.w = fq1(va.w, sA) * fq1(vb.w, sB);
    *(float4*)(o + i) = r;
    float mx = fmaxf(fmaxf(fabsf(r.x), fabsf(r.y)), fmaxf(fabsf(r.z), fabsf(r.w)));
    __shared__ float sd[4];
    block_amax(mx, amO, sd);
}

__global__ __launch_bounds__(256) void k_sig(const float* a, const float* amA,
                                             float* o, float* amO) {
    const float sA = qscale(amA);
    const int i = (blockIdx.x * 256 + threadIdx.x) * 4;
    float4 v = *(const float4*)(a + i);
    float4 r;
    r.x = sigm(fq1(v.x, sA)); r.y = sigm(fq1(v.y, sA));
    r.z = sigm(fq1(v.z, sA)); r.w = sigm(fq1(v.w, sA));
    *(float4*)(o + i) = r;
    float mx = fmaxf(fmaxf(fabsf(r.x), fabsf(r.y)), fmaxf(fabsf(r.z), fabsf(r.w)));
    __shared__ float sd[4];
    block_amax(mx, amO, sd);
}

__global__ __launch_bounds__(256) void k_tanh(const float* a, const float* amA,
                                              float* o, float* amO) {
    const float sA = qscale(amA);
    const int i = (blockIdx.x * 256 + threadIdx.x) * 4;
    float4 v = *(const float4*)(a + i);
    float4 r;
    r.x = tanhf(fq1(v.x, sA)); r.y = tanhf(fq1(v.y, sA));
    r.z = tanhf(fq1(v.z, sA)); r.w = tanhf(fq1(v.w, sA));
    *(float4*)(o + i) = r;
    float mx = fmaxf(fmaxf(fabsf(r.x), fabsf(r.y)), fmaxf(fabsf(r.z), fabsf(r.w)));
    __shared__ float sd[4];
    block_amax(mx, amO, sd);
}

__global__ __launch_bounds__(256) void k_relu(const float* a, const float* amA,
                                              float* o, float* amO) {
    const float sA = qscale(amA);
    const int i = (blockIdx.x * 256 + threadIdx.x) * 4;
    float4 v = *(const float4*)(a + i);
    float4 r;
    r.x = fmaxf(0.f, fq1(v.x, sA)); r.y = fmaxf(0.f, fq1(v.y, sA));
    r.z = fmaxf(0.f, fq1(v.z, sA)); r.w = fmaxf(0.f, fq1(v.w, sA));
    *(float4*)(o + i) = r;
    float mx = fmaxf(fmaxf(fabsf(r.x), fabsf(r.y)), fmaxf(fabsf(r.z), fabsf(r.w)));
    __shared__ float sd[4];
    block_amax(mx, amO, sd);
}

__global__ __launch_bounds__(256) void k_omzzh(const float* z, const float* amZ,
                                               const float* h, const float* amH,
                                               float* omz, float* amOmz,
                                               float* zh, float* amZh) {
    const float sZ = qscale(amZ), sH = qscale(amH);
    const int i = (blockIdx.x * 256 + threadIdx.x) * 4;
    float4 zv = *(const float4*)(z + i);
    float4 hv = *(const float4*)(h + i);
    float zq[4] = {fq1(zv.x, sZ), fq1(zv.y, sZ), fq1(zv.z, sZ), fq1(zv.w, sZ)};
    float hq[4] = {fq1(hv.x, sH), fq1(hv.y, sH), fq1(hv.z, sH), fq1(hv.w, sH)};
    float4 o, p;
    o.x = 1.f - zq[0]; o.y = 1.f - zq[1]; o.z = 1.f - zq[2]; o.w = 1.f - zq[3];
    p.x = zq[0] * hq[0]; p.y = zq[1] * hq[1]; p.z = zq[2] * hq[2]; p.w = zq[3] * hq[3];
    *(float4*)(omz + i) = o;
    *(float4*)(zh + i) = p;
    float mo = fmaxf(fmaxf(fabsf(o.x), fabsf(o.y)), fmaxf(fabsf(o.z), fabsf(o.w)));
    float mp = fmaxf(fmaxf(fabsf(p.x), fabsf(p.y)), fmaxf(fabsf(p.z), fabsf(p.w)));
    __shared__ float sd[8];
    block_amax(mo, amOmz, sd);
    block_amax(mp, amZh, sd + 4);
}

__global__ __launch_bounds__(256) void k_out(const float* sg, const float* AMall,
                                             float* out) {
    float c = -1.f;
    if (AMall[120] != MAGIC) c = 3.5f;
    else if (!(AMall[0]  > 1e-9f)) c = 10.f;
    else if (!(AMall[35] > 1e-9f)) c = 11.f;
    else if (!(AMall[36] > 1e-9f)) c = 12.f;
    else if (!(AMall[59] > 1e-9f)) c = 13.f;
    else if (!(AMall[82] > 1e-9f)) c = 14.f;
    else if (!(AMall[90] > 1e-9f)) c = 15.f;
    else if (!(AMall[91] > 1e-6f)) c = 16.f;
    const int i = (blockIdx.x * 256 + threadIdx.x) * 4;
    if (c >= 0.f) {
        out[i] = c; out[i + 1] = c; out[i + 2] = c; out[i + 3] = c;
        return;
    }
    const float s = AMall[91] / 127.0f + 1e-12f;
    float4 v = *(const float4*)(sg + i);
    float4 r;
    r.x = fq1(v.x, s); r.y = fq1(v.y, s); r.z = fq1(v.z, s); r.w = fq1(v.w, s);
    if (!(fabsf(r.x) <= 1.5f)) r.x = 4.5f;
    if (!(fabsf(r.y) <= 1.5f)) r.y = 4.5f;
    if (!(fabsf(r.z) <= 1.5f)) r.z = 4.5f;
    if (!(fabsf(r.w) <= 1.5f)) r.w = 4.5f;
    *(float4*)(out + i) = r;
}

// ---------------- host orchestration ----------------
extern "C" void kernel_launch(void* const* d_in, const int* in_sizes, int n_in,
                              void* d_out, int out_size, void* d_ws, size_t ws_size,
                              hipStream_t stream) {
    const float* in[35];
    for (int i = 0; i < 35; ++i) in[i] = (const float*)d_in[i];
    float* fout = (float*)d_out;

    const size_t NEED_MID = (size_t)(128 + 4 * (size_t)R4 + ARENA_F) * 4;  // 30.21 MB
    const size_t NEED_BIG = (size_t)(128 + 6 * (size_t)R4 + ARENA_F) * 4;  // 43.32 MB
    if (ws_size < NEED_MID) {
        k_fill<<<(out_size + 255) / 256, 256, 0, stream>>>(fout, out_size, 0.25f);
        return;
    }
    const bool big = (ws_size >= NEED_BIG);

    float* AM = (float*)d_ws;
    float* X  = AM + 128;
    float* A  = X + R4;
    float* B  = A + R4;
    float* C  = B + R4;
    float* F1 = A;                         // 600-row views (3*R4 == 2*R6)
    float* F2 = A + R6;
    float* D  = big ? (C + R4) : nullptr;
    float* E  = big ? (D + R4) : nullptr;
    float* WA = big ? (E + R4) : (C + R4); // arena, ARENA_F floats

    const int I_OFF = 0, H_OFF = 499200, MAT = 166400;  // 400x416 per mat

    k_init<<<1, 128, 0, stream>>>(AM);

    AbsmaxArgs aa;
    for (int i = 0; i < 35; ++i) { aa.p[i] = in[i]; aa.n[i] = in_sizes[i]; }
    aa.am = AM;
    absmax_multi<<<dim3(16, 35), 256, 0, stream>>>(aa);

    auto dqw = [&](const int* ins, const int* offs, const int* Ms, const int* Ks,
                   const int* Kps, int cnt) {
        DqwArgs d{};
        for (int i = 0; i < cnt; ++i) {
            d.src[i] = in[ins[i]]; d.off[i] = offs[i]; d.M[i] = Ms[i];
            d.K[i] = Ks[i]; d.Kp[i] = Kps[i]; d.amIdx[i] = ins[i];
        }
        k_dqw<<<dim3(48, cnt), 256, 0, stream>>>(d, WA, AM);
    };
    auto bias = [&](float* T, int amT, const float* bv, int amB_, int amU, int M) {
        k_bias<<<M * 4, 256, 0, stream>>>(T, AM + amT, bv, AM + amB_, T, AM + amU);
    };
    auto bias3 = [&](float* t0, float* t1, float* t2, const float* b0, const float* b1,
                     const float* b2, int aT0, int aT1, int aT2, int aB0, int aB1,
                     int aB2, int aU0, int aU1, int aU2) {
        Bias3Args a;
        a.t[0] = t0; a.t[1] = t1; a.t[2] = t2;
        a.bias[0] = b0; a.bias[1] = b1; a.bias[2] = b2;
        a.amT[0] = aT0; a.amT[1] = aT1; a.amT[2] = aT2;
        a.amB[0] = aB0; a.amB[1] = aB1; a.amB[2] = aB2;
        a.amU[0] = aU0; a.amU[1] = aU1; a.amU[2] = aU2;
        k_bias3<<<1200 * 4, 256, 0, stream>>>(a, AM);
    };
    auto add = [&](const float* a, int ama, const float* b, int amb, float* o, int amo, int M) {
        k_add<<<M * 4, 256, 0, stream>>>(a, AM + ama, b, AM + amb, o, AM + amo);
    };
    auto mul = [&](const float* a, int ama, const float* b, int amb, float* o, int amo, int M) {
        k_mul<<<M * 4, 256, 0, stream>>>(a, AM + ama, b, AM + amb, o, AM + amo);
    };
    auto sig = [&](float* a, int ama, int amo, int M) {
        k_sig<<<M * 4, 256, 0, stream>>>(a, AM + ama, a, AM + amo);
    };
    auto tnh = [&](float* a, int ama, int amo, int M) {
        k_tanh<<<M * 4, 256, 0, stream>>>(a, AM + ama, a, AM + amo);
    };
    auto relu = [&](float* a, int ama, int amo, int M) {
        k_relu<<<M * 4, 256, 0, stream>>>(a, AM + ama, a, AM + amo);
    };
    auto dqa = [&](float* x, int am, int nrows) {
        k_dqa<<<nrows * 4, 256, 0, stream>>>(x, AM + am);
    };

    // ---- fc1 (arena: fc1 weights only, then overwritten by GRU1) ----
    { const int i_[1] = {3}, o_[1] = {0}, m_[1] = {400}, k_[1] = {257}, p_[1] = {288};
      dqw(i_, o_, m_, k_, p_, 1); }
    gemm_k<2, true><<<dim3(64, 13), 256, 0, stream>>>(
        WA, in[0], AM + 0, X, X, X, AM + 35, AM + 35, AM + 35, 400, 257, 288, 400, 1);
    bias(X, 35, in[4], 4, 36, 400);
    dqa(X, 36, 400);

    // ---- GRU ----
    auto gru = [&](int wb, const float* h, int amH, int ab) {
        // dequant 6 mats: i-stack {Wir,Wiz,Win}, h-stack {Whr,Whz,Whn}
        { const int i_[6] = {wb, wb + 4, wb + 8, wb + 1, wb + 5, wb + 9};
          const int o_[6] = {I_OFF, I_OFF + MAT, I_OFF + 2 * MAT,
                             H_OFF, H_OFF + MAT, H_OFF + 2 * MAT};
          const int m_[6] = {400, 400, 400, 400, 400, 400};
          const int k_[6] = {400, 400, 400, 400, 400, 400};
          const int p_[6] = {416, 416, 416, 416, 416, 416};
          dqw(i_, o_, m_, k_, p_, 6); }
        // Gi3: a->A, c->B, e->C  (X pre-fq'd)
        gemm_k<4, false><<<dim3(64, 19), 256, 0, stream>>>(
            WA + I_OFF, X, AM, A, B, C,
            AM + ab + 0, AM + ab + 6, AM + ab + 15, 1200, 400, 416, 400, 3);
        bias3(A, B, C, in[wb + 2], in[wb + 6], in[wb + 10],
              ab + 0, ab + 6, ab + 15, wb + 2, wb + 6, wb + 10,
              ab + 1, ab + 7, ab + 16);
        if (big) {
            // Gh3: b->D, d->E, f->X (h raw, fq on staging)
            gemm_k<4, true><<<dim3(64, 19), 256, 0, stream>>>(
                WA + H_OFF, h, AM + amH, D, E, X,
                AM + ab + 2, AM + ab + 8, AM + ab + 12, 1200, 400, 416, 400, 3);
            bias3(D, E, X, in[wb + 3], in[wb + 7], in[wb + 11],
                  ab + 2, ab + 8, ab + 12, wb + 3, wb + 7, wb + 11,
                  ab + 3, ab + 9, ab + 13);
            add(A, ab + 1, D, ab + 3, A, ab + 4, 400);  sig(A, ab + 4, ab + 5, 400);   // r
            add(B, ab + 7, E, ab + 9, B, ab + 10, 400); sig(B, ab + 10, ab + 11, 400); // z
            mul(A, ab + 5, X, ab + 13, A, ab + 14, 400);                                // rf
            add(C, ab + 16, A, ab + 14, C, ab + 17, 400); tnh(C, ab + 17, ab + 18, 400);// tn
            k_omzzh<<<400 * 4, 256, 0, stream>>>(B, AM + ab + 11, h, AM + amH,
                                                 D, AM + ab + 19, E, AM + ab + 20);
            mul(D, ab + 19, C, ab + 18, C, ab + 21, 400);                               // t2
            add(C, ab + 21, E, ab + 20, X, ab + 22, 400);                               // g->X
        } else {
            // 3 separate h-side GEMMs through X
            gemm_k<2, true><<<dim3(64, 13), 256, 0, stream>>>(
                WA + H_OFF, h, AM + amH, X, X, X,
                AM + ab + 2, AM + ab + 2, AM + ab + 2, 400, 400, 416, 400, 1);
            bias(X, ab + 2, in[wb + 3], wb + 3, ab + 3, 400);                           // b
            add(A, ab + 1, X, ab + 3, A, ab + 4, 400);  sig(A, ab + 4, ab + 5, 400);    // r
            gemm_k<2, true><<<dim3(64, 13), 256, 0, stream>>>(
                WA + H_OFF + MAT, h, AM + amH, X, X, X,
                AM + ab + 8, AM + ab + 8, AM + ab + 8, 400, 400, 416, 400, 1);
            bias(X, ab + 8, in[wb + 7], wb + 7, ab + 9, 400);                           // d
            add(B, ab + 7, X, ab + 9, B, ab + 10, 400); sig(B, ab + 10, ab + 11, 400);  // z
            gemm_k<2, true><<<dim3(64, 13), 256, 0, stream>>>(
                WA + H_OFF + 2 * MAT, h, AM + amH, X, X, X,
                AM + ab + 12, AM + ab + 12, AM + ab + 12, 400, 400, 416, 400, 1);
            bias(X, ab + 12, in[wb + 11], wb + 11, ab + 13, 400);                       // f
            mul(A, ab + 5, X, ab + 13, A, ab + 14, 400);                                // rf
            add(C, ab + 16, A, ab + 14, C, ab + 17, 400); tnh(C, ab + 17, ab + 18, 400);// tn
            k_omzzh<<<400 * 4, 256, 0, stream>>>(B, AM + ab + 11, h, AM + amH,
                                                 A, AM + ab + 19, X, AM + ab + 20);
            mul(A, ab + 19, C, ab + 18, C, ab + 21, 400);                               // t2
            add(C, ab + 21, X, ab + 20, X, ab + 22, 400);                               // g->X
        }
    };

    gru(5, in[1], 1, 37);      // g1 -> X, am 59
    dqa(X, 59, 400);
    gru(17, in[2], 2, 60);     // g2 -> X, am 82
    dqa(X, 82, 400);

    // ---- FC section (arena: fc2@0, fc3@249600, fc4@614400) ----
    { const int i_[3] = {29, 31, 33}, o_[3] = {0, 249600, 614400};
      const int m_[3] = {600, 600, 257}, k_[3] = {400, 600, 600}, p_[3] = {416, 608, 608};
      dqw(i_, o_, m_, k_, p_, 3); }

    gemm_k<4, false><<<dim3(64, 10), 256, 0, stream>>>(
        WA, X, AM, F1, F1, F1, AM + 83, AM + 83, AM + 83, 600, 400, 416, 600, 1);
    bias(F1, 83, in[30], 30, 84, 600);
    relu(F1, 84, 85, 600);
    dqa(F1, 85, 600);

    gemm_k<4, false><<<dim3(64, 10), 256, 0, stream>>>(
        WA + 249600, F1, AM, F2, F2, F2, AM + 86, AM + 86, AM + 86, 600, 600, 608, 600, 1);
    bias(F2, 86, in[32], 32, 87, 600);
    relu(F2, 87, 88, 600);
    dqa(F2, 88, 600);

    gemm_k<2, false><<<dim3(64, 9), 256, 0, stream>>>(
        WA + 614400, F2, AM, X, X, X, AM + 89, AM + 89, AM + 89, 257, 600, 608, 257, 1);
    bias(X, 89, in[34], 34, 90, 257);
    sig(X, 90, 91, 257);
    k_out<<<257 * 4, 256, 0, stream>>>(X, AM, fout);

    (void)n_in; (void)ws_size; (void)in_sizes;
}

// Round 10
// 1044.998 us; speedup vs baseline: 2.2636x; 1.9638x over previous
//
#include <hip/hip_runtime.h>

// Q_NsNet2: fake-quantized FC + 2xGRU + FC stack. Output f32.
// ROUND 10: bit-identical numerics to rounds 5/7/9 (PASS, absmax 0.015625).
// Theory: round-9 counters show atomic-serialization-bound (k_bias3 148us,
// VALU 3%, HBM 3%: 4800 same-cache-line atomicMax @ ~30ns). Fixes (all
// order-invariant max-reduction changes => bitwise exact):
//  - AM slots padded to 1 cache line (stride 32 floats)
//  - elementwise: 16 floats/thread, grid=M blocks, 1 block atomic (was 4M)
//  - gemm epilogue: per-block seg-deduped atomics (was per-wave)

#define BATCH_N 4096
#define R4 (400 * 4096)
#define R6 (600 * 4096)
#define MAGIC 123.0f
#define ARENA_F 998400          // floats: 2x 1200x416 stacks
#define AMF 4096                // padded AM region (floats); slot i at i*32

__device__ __forceinline__ float qscale(const float* am) { return am[0] / 127.0f + 1e-12f; }
__device__ __forceinline__ float qscale_v(float amv) { return amv / 127.0f + 1e-12f; }

__device__ __forceinline__ float fq1(float x, float s) {
    float q = rintf(x / s);                    // round-half-even, IEEE divide
    q = fminf(fmaxf(q, -127.0f), 127.0f);
    return q * s;
}

__device__ __forceinline__ float sigm(float x) {
    if (x >= 0.f) { float e = expf(-x); return 1.0f / (1.0f + e); }
    float e = expf(x); return e / (1.0f + e);
}

__device__ __forceinline__ float wave_max64(float v) {
#pragma unroll
    for (int off = 32; off > 0; off >>= 1)
        v = fmaxf(v, __shfl_down(v, off, 64));
    return v;
}

// Block-wide absmax -> ONE atomicMax per block (float-as-uint exact for >=0).
__device__ __forceinline__ void block_amax(float v, float* slot, float* sd) {
    v = wave_max64(v);
    int lane = threadIdx.x & 63, w = threadIdx.x >> 6;
    if (lane == 0) sd[w] = v;
    __syncthreads();
    if (threadIdx.x == 0) {
        int nw = blockDim.x >> 6;
        float m = sd[0];
        for (int i = 1; i < nw; ++i) m = fmaxf(m, sd[i]);
        atomicMax((unsigned int*)slot, __float_as_uint(m));
    }
}

__global__ void k_init(float* am) {
    int i = blockIdx.x * 256 + threadIdx.x;
    if (i < AMF) am[i] = (i == 120 * 32) ? MAGIC : 0.f;
}

__global__ void k_fill(float* out, int n, float c) {
    int i = blockIdx.x * 256 + threadIdx.x;
    if (i < n) out[i] = c;
}

// ---- input absmax: multi-block + atomicMax into padded slot ----
struct AbsmaxArgs { const float* p[35]; int n[35]; float* am; };

__global__ __launch_bounds__(256) void absmax_multi(AbsmaxArgs a) {
    int t = blockIdx.y;
    const float* p = a.p[t];
    int n = a.n[t];
    int nv = n >> 2;
    float v = 0.f;
    for (int i = blockIdx.x * 256 + threadIdx.x; i < nv; i += gridDim.x * 256) {
        float4 x = *(const float4*)(p + (size_t)i * 4);
        v = fmaxf(v, fmaxf(fmaxf(fabsf(x.x), fabsf(x.y)), fmaxf(fabsf(x.z), fabsf(x.w))));
    }
    for (int i = nv * 4 + blockIdx.x * 256 + threadIdx.x; i < n; i += gridDim.x * 256)
        v = fmaxf(v, fabsf(p[i]));
    __shared__ float sd[4];
    block_amax(v, a.am + (t << 5), sd);
}

// ---- weight dequant into padded arena: wd[m][k<K]=fq1(src), pad=0 ----
struct DqwArgs { const float* src[8]; int off[8], M[8], K[8], Kp[8], amIdx[8]; };

__global__ __launch_bounds__(256) void k_dqw(DqwArgs a, float* wd, const float* AM) {
    int t = blockIdx.y;
    const float s = qscale_v(AM[a.amIdx[t] << 5]);
    const float* src = a.src[t];
    float* dst = wd + a.off[t];
    int K = a.K[t], Kp = a.Kp[t], MK = a.M[t] * Kp;
    for (int e = blockIdx.x * 256 + threadIdx.x; e < MK; e += gridDim.x * 256) {
        int m = e / Kp, k = e - m * Kp;
        dst[e] = (k < K) ? fq1(src[(size_t)m * K + k], s) : 0.f;
    }
}

// ---- in-place activation fq (bitwise idempotent), 16 floats/thread ----
__global__ __launch_bounds__(256) void k_dqa(float* x, const float* am) {
    const float s = qscale(am);
    const int base = blockIdx.x * 4096;
#pragma unroll
    for (int j = 0; j < 4; ++j) {
        int i = base + (j * 256 + threadIdx.x) * 4;
        float4 v = *(const float4*)(x + i);
        v.x = fq1(v.x, s); v.y = fq1(v.y, s); v.z = fq1(v.z, s); v.w = fq1(v.w, s);
        *(float4*)(x + i) = v;
    }
}

// ---- GEMM: out = Wd(padded, pre-fq) @ B, fused segmented absmax.
// TM rows x 4 cols per thread; BM=16*TM, BN=64, BK=32; 256 threads.
template<int TM, bool FQB>
__global__ __launch_bounds__(256) void gemm_k(
    const float* __restrict__ Wd, const float* __restrict__ Bop,
    const float* __restrict__ amB,
    float* __restrict__ o0, float* __restrict__ o1, float* __restrict__ o2,
    float* __restrict__ a0, float* __restrict__ a1, float* __restrict__ a2,
    int M, int K, int Kp, int seg_rows, int nseg) {
    constexpr int BM = 16 * TM;
    __shared__ float As[32][BM + 4];
    __shared__ float Bs[32][64];
    __shared__ float sdm[4];
    __shared__ int sds[4];
    float sB = 0.f;
    if (FQB) sB = qscale(amB);
    const int bm = blockIdx.y * BM, bn = blockIdx.x * 64;
    const int tid = threadIdx.x;
    const int tx = tid & 15, ty = tid >> 4;
    float acc[TM][4] = {};

    for (int k0 = 0; k0 < Kp; k0 += 32) {
#pragma unroll
        for (int j = 0; j < TM / 2; ++j) {       // A: BM x 32, padded & aligned
            int q = j * 256 + tid;
            int m = q >> 3, kq = q & 7;
            int gm = bm + m;
            float4 v = make_float4(0.f, 0.f, 0.f, 0.f);
            if (gm < M) v = *(const float4*)(Wd + (size_t)gm * Kp + k0 + kq * 4);
            As[kq * 4 + 0][m] = v.x;
            As[kq * 4 + 1][m] = v.y;
            As[kq * 4 + 2][m] = v.z;
            As[kq * 4 + 3][m] = v.w;
        }
#pragma unroll
        for (int i = 0; i < 8; ++i) {            // B: 32 x 64, coalesced
            int e = i * 256 + tid;
            int c = e >> 6, j2 = e & 63;
            int gk = k0 + c;
            float v = 0.f;
            if (gk < K) {
                v = Bop[(size_t)gk * BATCH_N + bn + j2];
                if (FQB) v = fq1(v, sB);
            }
            Bs[c][j2] = v;
        }
        __syncthreads();
#pragma unroll
        for (int kk = 0; kk < 32; ++kk) {
            float4 b4 = *(const float4*)&Bs[kk][tx * 4];
            float bv[4] = {b4.x, b4.y, b4.z, b4.w};
            float av[TM];
#pragma unroll
            for (int i2 = 0; i2 < TM; ++i2) av[i2] = As[kk][ty * TM + i2];
#pragma unroll
            for (int i2 = 0; i2 < TM; ++i2)
#pragma unroll
                for (int j2 = 0; j2 < 4; ++j2)
                    acc[i2][j2] = fmaf(av[i2], bv[j2], acc[i2][j2]);
        }
        __syncthreads();
    }

    // epilogue: seg is wave-uniform (seg_rows % 16 == 0); per-block dedup.
    int gm0 = bm + ty * TM;
    int seg = gm0 / seg_rows;
    if (seg > nseg - 1) seg = nseg - 1;
    float* outp = (seg == 0) ? o0 : ((seg == 1) ? o1 : o2);
    int lrow0 = gm0 - seg * seg_rows;
    float mx = 0.f;
#pragma unroll
    for (int i = 0; i < TM; ++i) {
        if (gm0 + i < M) {
            float4 r;
            r.x = acc[i][0]; r.y = acc[i][1]; r.z = acc[i][2]; r.w = acc[i][3];
            *(float4*)(outp + (size_t)(lrow0 + i) * BATCH_N + bn + tx * 4) = r;
            mx = fmaxf(mx, fmaxf(fmaxf(fabsf(r.x), fabsf(r.y)), fmaxf(fabsf(r.z), fabsf(r.w))));
        }
    }
    mx = wave_max64(mx);
    int w = tid >> 6;
    if ((tid & 63) == 0) { sdm[w] = mx; sds[w] = seg; }
    __syncthreads();
    if (tid == 0) {
#pragma unroll
        for (int u = 0; u < 4; ++u) {
            int s = sds[u];
            if (s < 0) continue;
            float m = sdm[u];
            for (int v2 = u + 1; v2 < 4; ++v2)
                if (sds[v2] == s) { m = fmaxf(m, sdm[v2]); sds[v2] = -1; }
            float* amp = (s == 0) ? a0 : ((s == 1) ? a1 : a2);
            atomicMax((unsigned int*)amp, __float_as_uint(m));
        }
    }
}

// ------------- elementwise passes: 16 floats/thread, grid = M blocks -------------

__global__ __launch_bounds__(256) void k_bias(const float* t, const float* amT,
                                              const float* b, const float* amB,
                                              float* u, float* amU) {
    const float sT = qscale(amT), sB = qscale(amB);
    const int base = blockIdx.x * 4096;
    const float bb = fq1(b[blockIdx.x], sB);   // one row per block
    float mx = 0.f;
    __shared__ float sd[4];
#pragma unroll
    for (int j = 0; j < 4; ++j) {
        int i = base + (j * 256 + threadIdx.x) * 4;
        float4 v = *(const float4*)(t + i);
        float4 r;
        r.x = fq1(v.x, sT) + bb; r.y = fq1(v.y, sT) + bb;
        r.z = fq1(v.z, sT) + bb; r.w = fq1(v.w, sT) + bb;
        *(float4*)(u + i) = r;
        mx = fmaxf(mx, fmaxf(fmaxf(fabsf(r.x), fabsf(r.y)), fmaxf(fabsf(r.z), fabsf(r.w))));
    }
    block_amax(mx, amU, sd);
}

// 3-tensor bias over stacked rows [1200][4096]; one row per block
struct Bias3Args { float* t[3]; const float* bias[3]; int amT[3], amB[3], amU[3]; };

__global__ __launch_bounds__(256) void k_bias3(Bias3Args a, float* AM) {
    const int row = blockIdx.x;
    const int seg = row / 400;
    const int lrow = row - seg * 400;
    const float sT = qscale_v(AM[a.amT[seg]]);
    const float sB = qscale_v(AM[a.amB[seg]]);
    const float bb = fq1(a.bias[seg][lrow], sB);
    float* t = a.t[seg] + (size_t)lrow * BATCH_N;
    float mx = 0.f;
    __shared__ float sd[4];
#pragma unroll
    for (int j = 0; j < 4; ++j) {
        int i = (j * 256 + threadIdx.x) * 4;
        float4 v = *(const float4*)(t + i);
        float4 r;
        r.x = fq1(v.x, sT) + bb; r.y = fq1(v.y, sT) + bb;
        r.z = fq1(v.z, sT) + bb; r.w = fq1(v.w, sT) + bb;
        *(float4*)(t + i) = r;
        mx = fmaxf(mx, fmaxf(fmaxf(fabsf(r.x), fabsf(r.y)), fmaxf(fabsf(r.z), fabsf(r.w))));
    }
    block_amax(mx, AM + a.amU[seg], sd);
}

__global__ __launch_bounds__(256) void k_add(const float* a, const float* amA,
                                             const float* b, const float* amB,
                                             float* o, float* amO) {
    const float sA = qscale(amA), sB = qscale(amB);
    const int base = blockIdx.x * 4096;
    float mx = 0.f;
    __shared__ float sd[4];
#pragma unroll
    for (int j = 0; j < 4; ++j) {
        int i = base + (j * 256 + threadIdx.x) * 4;
        float4 va = *(const float4*)(a + i);
        float4 vb = *(const float4*)(b + i);
        float4 r;
        r.x = fq1(va.x, sA) + fq1(vb.x, sB); r.y = fq1(va.y, sA) + fq1(vb.y, sB);
        r.z = fq1(va.z, sA) + fq1(vb.z, sB); r.w = fq1(va.w, sA) + fq1(vb.w, sB);
        *(float4*)(o + i) = r;
        mx = fmaxf(mx, fmaxf(fmaxf(fabsf(r.x), fabsf(r.y)), fmaxf(fabsf(r.z), fabsf(r.w))));
    }
    block_amax(mx, amO, sd);
}

__global__ __launch_bounds__(256) void k_mul(const float* a, const float* amA,
                                             const float* b, const float* amB,
                                             float* o, float* amO) {
    const float sA = qscale(amA), sB = qscale(amB);
    const int base = blockIdx.x * 4096;
    float mx = 0.f;
    __shared__ float sd[4];
#pragma unroll
    for (int j = 0; j < 4; ++j) {
        int i = base + (j * 256 + threadIdx.x) * 4;
        float4 va = *(const float4*)(a + i);
        float4 vb = *(const float4*)(b + i);
        float4 r;
        r.x = fq1(va.x, sA) * fq1(vb.x, sB); r.y = fq1(va.y, sA) * fq1(vb.y, sB);
        r.z = fq1(va.z, sA) * fq1(vb.z, sB); r.w = fq1(va.w, sA) * fq1(vb.w, sB);
        *(float4*)(o + i) = r;
        mx = fmaxf(mx, fmaxf(fmaxf(fabsf(r.x), fabsf(r.y)), fmaxf(fabsf(r.z), fabsf(r.w))));
    }
    block_amax(mx, amO, sd);
}

__global__ __launch_bounds__(256) void k_sig(const float* a, const float* amA,
                                             float* o, float* amO) {
    const float sA = qscale(amA);
    const int base = blockIdx.x * 4096;
    float mx = 0.f;
    __shared__ float sd[4];
#pragma unroll
    for (int j = 0; j < 4; ++j) {
        int i = base + (j * 256 + threadIdx.x) * 4;
        float4 v = *(const float4*)(a + i);
        float4 r;
        r.x = sigm(fq1(v.x, sA)); r.y = sigm(fq1(v.y, sA));
        r.z = sigm(fq1(v.z, sA)); r.w = sigm(fq1(v.w, sA));
        *(float4*)(o + i) = r;
        mx = fmaxf(mx, fmaxf(fmaxf(fabsf(r.x), fabsf(r.y)), fmaxf(fabsf(r.z), fabsf(r.w))));
    }
    block_amax(mx, amO, sd);
}

__global__ __launch_bounds__(256) void k_tanh(const float* a, const float* amA,
                                              float* o, float* amO) {
    const float sA = qscale(amA);
    const int base = blockIdx.x * 4096;
    float mx = 0.f;
    __shared__ float sd[4];
#pragma unroll
    for (int j = 0; j < 4; ++j) {
        int i = base + (j * 256 + threadIdx.x) * 4;
        float4 v = *(const float4*)(a + i);
        float4 r;
        r.x = tanhf(fq1(v.x, sA)); r.y = tanhf(fq1(v.y, sA));
        r.z = tanhf(fq1(v.z, sA)); r.w = tanhf(fq1(v.w, sA));
        *(float4*)(o + i) = r;
        mx = fmaxf(mx, fmaxf(fmaxf(fabsf(r.x), fabsf(r.y)), fmaxf(fabsf(r.z), fabsf(r.w))));
    }
    block_amax(mx, amO, sd);
}

__global__ __launch_bounds__(256) void k_relu(const float* a, const float* amA,
                                              float* o, float* amO) {
    const float sA = qscale(amA);
    const int base = blockIdx.x * 4096;
    float mx = 0.f;
    __shared__ float sd[4];
#pragma unroll
    for (int j = 0; j < 4; ++j) {
        int i = base + (j * 256 + threadIdx.x) * 4;
        float4 v = *(const float4*)(a + i);
        float4 r;
        r.x = fmaxf(0.f, fq1(v.x, sA)); r.y = fmaxf(0.f, fq1(v.y, sA));
        r.z = fmaxf(0.f, fq1(v.z, sA)); r.w = fmaxf(0.f, fq1(v.w, sA));
        *(float4*)(o + i) = r;
        mx = fmaxf(mx, fmaxf(fmaxf(fabsf(r.x), fabsf(r.y)), fmaxf(fabsf(r.z), fabsf(r.w))));
    }
    block_amax(mx, amO, sd);
}

__global__ __launch_bounds__(256) void k_omzzh(const float* z, const float* amZ,
                                               const float* h, const float* amH,
                                               float* omz, float* amOmz,
                                               float* zh, float* amZh) {
    const float sZ = qscale(amZ), sH = qscale(amH);
    const int base = blockIdx.x * 4096;
    float mo = 0.f, mp = 0.f;
    __shared__ float sd[8];
#pragma unroll
    for (int j = 0; j < 4; ++j) {
        int i = base + (j * 256 + threadIdx.x) * 4;
        float4 zv = *(const float4*)(z + i);
        float4 hv = *(const float4*)(h + i);
        float zq[4] = {fq1(zv.x, sZ), fq1(zv.y, sZ), fq1(zv.z, sZ), fq1(zv.w, sZ)};
        float hq[4] = {fq1(hv.x, sH), fq1(hv.y, sH), fq1(hv.z, sH), fq1(hv.w, sH)};
        float4 o, p;
        o.x = 1.f - zq[0]; o.y = 1.f - zq[1]; o.z = 1.f - zq[2]; o.w = 1.f - zq[3];
        p.x = zq[0] * hq[0]; p.y = zq[1] * hq[1]; p.z = zq[2] * hq[2]; p.w = zq[3] * hq[3];
        *(float4*)(omz + i) = o;
        *(float4*)(zh + i) = p;
        mo = fmaxf(mo, fmaxf(fmaxf(fabsf(o.x), fabsf(o.y)), fmaxf(fabsf(o.z), fabsf(o.w))));
        mp = fmaxf(mp, fmaxf(fmaxf(fabsf(p.x), fabsf(p.y)), fmaxf(fabsf(p.z), fabsf(p.w))));
    }
    block_amax(mo, amOmz, sd);
    block_amax(mp, amZh, sd + 4);
}

__global__ __launch_bounds__(256) void k_out(const float* sg, const float* AMall,
                                             float* out) {
    float c = -1.f;
    if (AMall[120 * 32] != MAGIC) c = 3.5f;
    else if (!(AMall[0]       > 1e-9f)) c = 10.f;
    else if (!(AMall[35 * 32] > 1e-9f)) c = 11.f;
    else if (!(AMall[36 * 32] > 1e-9f)) c = 12.f;
    else if (!(AMall[59 * 32] > 1e-9f)) c = 13.f;
    else if (!(AMall[82 * 32] > 1e-9f)) c = 14.f;
    else if (!(AMall[90 * 32] > 1e-9f)) c = 15.f;
    else if (!(AMall[91 * 32] > 1e-6f)) c = 16.f;
    const int base = blockIdx.x * 4096;
    const float s = AMall[91 * 32] / 127.0f + 1e-12f;
#pragma unroll
    for (int j = 0; j < 4; ++j) {
        int i = base + (j * 256 + threadIdx.x) * 4;
        if (c >= 0.f) {
            out[i] = c; out[i + 1] = c; out[i + 2] = c; out[i + 3] = c;
            continue;
        }
        float4 v = *(const float4*)(sg + i);
        float4 r;
        r.x = fq1(v.x, s); r.y = fq1(v.y, s); r.z = fq1(v.z, s); r.w = fq1(v.w, s);
        if (!(fabsf(r.x) <= 1.5f)) r.x = 4.5f;
        if (!(fabsf(r.y) <= 1.5f)) r.y = 4.5f;
        if (!(fabsf(r.z) <= 1.5f)) r.z = 4.5f;
        if (!(fabsf(r.w) <= 1.5f)) r.w = 4.5f;
        *(float4*)(out + i) = r;
    }
}

// ---------------- host orchestration ----------------
extern "C" void kernel_launch(void* const* d_in, const int* in_sizes, int n_in,
                              void* d_out, int out_size, void* d_ws, size_t ws_size,
                              hipStream_t stream) {
    const float* in[35];
    for (int i = 0; i < 35; ++i) in[i] = (const float*)d_in[i];
    float* fout = (float*)d_out;

    const size_t NEED_MID = (size_t)(AMF + 4 * (size_t)R4 + ARENA_F) * 4;  // 30.2 MB
    const size_t NEED_BIG = (size_t)(AMF + 6 * (size_t)R4 + ARENA_F) * 4;  // 43.3 MB
    if (ws_size < NEED_MID) {
        k_fill<<<(out_size + 255) / 256, 256, 0, stream>>>(fout, out_size, 0.25f);
        return;
    }
    const bool big = (ws_size >= NEED_BIG);

    float* AM = (float*)d_ws;
    float* X  = AM + AMF;
    float* A  = X + R4;
    float* B  = A + R4;
    float* C  = B + R4;
    float* F1 = A;                         // 600-row views (3*R4 == 2*R6)
    float* F2 = A + R6;
    float* D  = big ? (C + R4) : nullptr;
    float* E  = big ? (D + R4) : nullptr;
    float* WA = big ? (E + R4) : (C + R4); // arena, ARENA_F floats

    const int I_OFF = 0, H_OFF = 499200, MAT = 166400;  // 400x416 per mat

    auto AMS = [&](int slot) { return AM + (slot << 5); };

    k_init<<<(AMF + 255) / 256, 256, 0, stream>>>(AM);

    AbsmaxArgs aa;
    for (int i = 0; i < 35; ++i) { aa.p[i] = in[i]; aa.n[i] = in_sizes[i]; }
    aa.am = AM;
    absmax_multi<<<dim3(16, 35), 256, 0, stream>>>(aa);

    auto dqw = [&](const int* ins, const int* offs, const int* Ms, const int* Ks,
                   const int* Kps, int cnt) {
        DqwArgs d{};
        for (int i = 0; i < cnt; ++i) {
            d.src[i] = in[ins[i]]; d.off[i] = offs[i]; d.M[i] = Ms[i];
            d.K[i] = Ks[i]; d.Kp[i] = Kps[i]; d.amIdx[i] = ins[i];
        }
        k_dqw<<<dim3(48, cnt), 256, 0, stream>>>(d, WA, AM);
    };
    auto bias = [&](float* T, int amT, const float* bv, int amB_, int amU, int M) {
        k_bias<<<M, 256, 0, stream>>>(T, AMS(amT), bv, AMS(amB_), T, AMS(amU));
    };
    auto bias3 = [&](float* t0, float* t1, float* t2, const float* b0, const float* b1,
                     const float* b2, int aT0, int aT1, int aT2, int aB0, int aB1,
                     int aB2, int aU0, int aU1, int aU2) {
        Bias3Args a;
        a.t[0] = t0; a.t[1] = t1; a.t[2] = t2;
        a.bias[0] = b0; a.bias[1] = b1; a.bias[2] = b2;
        a.amT[0] = aT0 << 5; a.amT[1] = aT1 << 5; a.amT[2] = aT2 << 5;
        a.amB[0] = aB0 << 5; a.amB[1] = aB1 << 5; a.amB[2] = aB2 << 5;
        a.amU[0] = aU0 << 5; a.amU[1] = aU1 << 5; a.amU[2] = aU2 << 5;
        k_bias3<<<1200, 256, 0, stream>>>(a, AM);
    };
    auto add = [&](const float* a, int ama, const float* b, int amb, float* o, int amo, int M) {
        k_add<<<M, 256, 0, stream>>>(a, AMS(ama), b, AMS(amb), o, AMS(amo));
    };
    auto mul = [&](const float* a, int ama, const float* b, int amb, float* o, int amo, int M) {
        k_mul<<<M, 256, 0, stream>>>(a, AMS(ama), b, AMS(amb), o, AMS(amo));
    };
    auto sig = [&](float* a, int ama, int amo, int M) {
        k_sig<<<M, 256, 0, stream>>>(a, AMS(ama), a, AMS(amo));
    };
    auto tnh = [&](float* a, int ama, int amo, int M) {
        k_tanh<<<M, 256, 0, stream>>>(a, AMS(ama), a, AMS(amo));
    };
    auto relu = [&](float* a, int ama, int amo, int M) {
        k_relu<<<M, 256, 0, stream>>>(a, AMS(ama), a, AMS(amo));
    };
    auto dqa = [&](float* x, int am, int nrows) {
        k_dqa<<<nrows, 256, 0, stream>>>(x, AMS(am));
    };

    // ---- fc1 ----
    { const int i_[1] = {3}, o_[1] = {0}, m_[1] = {400}, k_[1] = {257}, p_[1] = {288};
      dqw(i_, o_, m_, k_, p_, 1); }
    gemm_k<2, true><<<dim3(64, 13), 256, 0, stream>>>(
        WA, in[0], AMS(0), X, X, X, AMS(35), AMS(35), AMS(35), 400, 257, 288, 400, 1);
    bias(X, 35, in[4], 4, 36, 400);
    dqa(X, 36, 400);

    // ---- GRU ----
    auto gru = [&](int wb, const float* h, int amH, int ab) {
        { const int i_[6] = {wb, wb + 4, wb + 8, wb + 1, wb + 5, wb + 9};
          const int o_[6] = {I_OFF, I_OFF + MAT, I_OFF + 2 * MAT,
                             H_OFF, H_OFF + MAT, H_OFF + 2 * MAT};
          const int m_[6] = {400, 400, 400, 400, 400, 400};
          const int k_[6] = {400, 400, 400, 400, 400, 400};
          const int p_[6] = {416, 416, 416, 416, 416, 416};
          dqw(i_, o_, m_, k_, p_, 6); }
        // Gi3: a->A, c->B, e->C  (X pre-fq'd)
        gemm_k<4, false><<<dim3(64, 19), 256, 0, stream>>>(
            WA + I_OFF, X, AM, A, B, C,
            AMS(ab + 0), AMS(ab + 6), AMS(ab + 15), 1200, 400, 416, 400, 3);
        bias3(A, B, C, in[wb + 2], in[wb + 6], in[wb + 10],
              ab + 0, ab + 6, ab + 15, wb + 2, wb + 6, wb + 10,
              ab + 1, ab + 7, ab + 16);
        if (big) {
            // Gh3: b->D, d->E, f->X (h raw, fq on staging)
            gemm_k<4, true><<<dim3(64, 19), 256, 0, stream>>>(
                WA + H_OFF, h, AMS(amH), D, E, X,
                AMS(ab + 2), AMS(ab + 8), AMS(ab + 12), 1200, 400, 416, 400, 3);
            bias3(D, E, X, in[wb + 3], in[wb + 7], in[wb + 11],
                  ab + 2, ab + 8, ab + 12, wb + 3, wb + 7, wb + 11,
                  ab + 3, ab + 9, ab + 13);
            add(A, ab + 1, D, ab + 3, A, ab + 4, 400);  sig(A, ab + 4, ab + 5, 400);   // r
            add(B, ab + 7, E, ab + 9, B, ab + 10, 400); sig(B, ab + 10, ab + 11, 400); // z
            mul(A, ab + 5, X, ab + 13, A, ab + 14, 400);                                // rf
            add(C, ab + 16, A, ab + 14, C, ab + 17, 400); tnh(C, ab + 17, ab + 18, 400);// tn
            k_omzzh<<<400, 256, 0, stream>>>(B, AMS(ab + 11), h, AMS(amH),
                                             D, AMS(ab + 19), E, AMS(ab + 20));
            mul(D, ab + 19, C, ab + 18, C, ab + 21, 400);                               // t2
            add(C, ab + 21, E, ab + 20, X, ab + 22, 400);                               // g->X
        } else {
            gemm_k<2, true><<<dim3(64, 13), 256, 0, stream>>>(
                WA + H_OFF, h, AMS(amH), X, X, X,
                AMS(ab + 2), AMS(ab + 2), AMS(ab + 2), 400, 400, 416, 400, 1);
            bias(X, ab + 2, in[wb + 3], wb + 3, ab + 3, 400);                           // b
            add(A, ab + 1, X, ab + 3, A, ab + 4, 400);  sig(A, ab + 4, ab + 5, 400);    // r
            gemm_k<2, true><<<dim3(64, 13), 256, 0, stream>>>(
                WA + H_OFF + MAT, h, AMS(amH), X, X, X,
                AMS(ab + 8), AMS(ab + 8), AMS(ab + 8), 400, 400, 416, 400, 1);
            bias(X, ab + 8, in[wb + 7], wb + 7, ab + 9, 400);                           // d
            add(B, ab + 7, X, ab + 9, B, ab + 10, 400); sig(B, ab + 10, ab + 11, 400);  // z
            gemm_k<2, true><<<dim3(64, 13), 256, 0, stream>>>(
                WA + H_OFF + 2 * MAT, h, AMS(amH), X, X, X,
                AMS(ab + 12), AMS(ab + 12), AMS(ab + 12), 400, 400, 416, 400, 1);
            bias(X, ab + 12, in[wb + 11], wb + 11, ab + 13, 400);                       // f
            mul(A, ab + 5, X, ab + 13, A, ab + 14, 400);                                // rf
            add(C, ab + 16, A, ab + 14, C, ab + 17, 400); tnh(C, ab + 17, ab + 18, 400);// tn
            k_omzzh<<<400, 256, 0, stream>>>(B, AMS(ab + 11), h, AMS(amH),
                                             A, AMS(ab + 19), X, AMS(ab + 20));
            mul(A, ab + 19, C, ab + 18, C, ab + 21, 400);                               // t2
            add(C, ab + 21, X, ab + 20, X, ab + 22, 400);                               // g->X
        }
    };

    gru(5, in[1], 1, 37);      // g1 -> X, am 59
    dqa(X, 59, 400);
    gru(17, in[2], 2, 60);     // g2 -> X, am 82
    dqa(X, 82, 400);

    // ---- FC section (arena: fc2@0, fc3@249600, fc4@614400) ----
    { const int i_[3] = {29, 31, 33}, o_[3] = {0, 249600, 614400};
      const int m_[3] = {600, 600, 257}, k_[3] = {400, 600, 600}, p_[3] = {416, 608, 608};
      dqw(i_, o_, m_, k_, p_, 3); }

    gemm_k<4, false><<<dim3(64, 10), 256, 0, stream>>>(
        WA, X, AM, F1, F1, F1, AMS(83), AMS(83), AMS(83), 600, 400, 416, 600, 1);
    bias(F1, 83, in[30], 30, 84, 600);
    relu(F1, 84, 85, 600);
    dqa(F1, 85, 600);

    gemm_k<4, false><<<dim3(64, 10), 256, 0, stream>>>(
        WA + 249600, F1, AM, F2, F2, F2, AMS(86), AMS(86), AMS(86), 600, 600, 608, 600, 1);
    bias(F2, 86, in[32], 32, 87, 600);
    relu(F2, 87, 88, 600);
    dqa(F2, 88, 600);

    gemm_k<2, false><<<dim3(64, 9), 256, 0, stream>>>(
        WA + 614400, F2, AM, X, X, X, AMS(89), AMS(89), AMS(89), 257, 600, 608, 257, 1);
    bias(X, 89, in[34], 34, 90, 257);
    sig(X, 90, 91, 257);
    k_out<<<257, 256, 0, stream>>>(X, AM, fout);

    (void)n_in; (void)ws_size; (void)in_sizes;
}